// Round 9
// baseline (845.958 us; speedup 1.0000x reference)
//
#include <hip/hip_runtime.h>
#include <math.h>

#define NN 8192
#define DF 768
#define NE_ 262144
#define DIM 1536
#define DSN 16
#define NCH 128
#define CL  64   // NN / NCH

typedef short short8 __attribute__((ext_vector_type(8)));
typedef float f32x4 __attribute__((ext_vector_type(4)));

__device__ __forceinline__ float bf2f(unsigned short u){
  unsigned int v = ((unsigned int)u) << 16; float f; __builtin_memcpy(&f, &v, 4); return f;
}
__device__ __forceinline__ unsigned short f2bf(float f){
  unsigned int x; __builtin_memcpy(&x, &f, 4);
  x += 0x7fffu + ((x >> 16) & 1u);
  return (unsigned short)(x >> 16);
}
__device__ __forceinline__ float sigmoidf_(float x){ return 1.f/(1.f+expf(-x)); }

// ---------------- prep kernels ----------------

__global__ void k_transpose_cast(const float* __restrict__ in, unsigned short* __restrict__ out,
                                 int K, int N, int Kp){
  int k = blockIdx.x*256 + threadIdx.x;
  int n = blockIdx.y;
  if (k >= Kp) return;
  unsigned short v = 0;
  if (k < K && n < N) v = f2bf(in[(size_t)k*N + n]);
  out[(size_t)n*Kp + k] = v;
}

// stable rank, 2D-parallel
__global__ __launch_bounds__(256) void k_rank(const int* __restrict__ ts, int* __restrict__ pos){
  __shared__ int sT[256];
  int i = blockIdx.x*256 + threadIdx.x;
  int my = ts[i];
  int c0 = blockIdx.y*256;
  sT[threadIdx.x] = ts[c0 + threadIdx.x];
  __syncthreads();
  int r = 0;
  #pragma unroll 8
  for (int j = 0; j < 256; j++){
    int t = sT[j]; int jj = c0 + j;
    r += (t < my || (t == my && jj < i)) ? 1 : 0;
  }
  atomicAdd(&pos[i], r);
}

__global__ void k_gather(const float* __restrict__ nf, const int* __restrict__ pos,
                         unsigned short* __restrict__ seq){
  int i = blockIdx.x; int p = pos[i];
  const float* src = nf + (size_t)i*DF;
  unsigned short* dst = seq + (size_t)p*DF;
  for (int j = threadIdx.x; j < DF; j += 256) dst[j] = f2bf(src[j]);
}

__global__ void k_deg_count(const int* __restrict__ esrc, const int* __restrict__ edst,
                            int* __restrict__ degS, int* __restrict__ degD){
  int e = blockIdx.x*256 + threadIdx.x;
  if (e < NE_){ atomicAdd(&degS[esrc[e]], 1); atomicAdd(&degD[edst[e]], 1); }
}

__global__ void k_norms(const int* __restrict__ degS, const int* __restrict__ degD,
                        float* __restrict__ normS, float* __restrict__ normD){
  int i = blockIdx.x*256 + threadIdx.x;
  if (i < NN){
    normS[i] = rsqrtf(fmaxf((float)degS[i], 1.f));
    normD[i] = rsqrtf(fmaxf((float)degD[i], 1.f));
  }
}

__global__ __launch_bounds__(1024) void k_rowptr(const int* __restrict__ degD,
                                                 int* __restrict__ row_ptr, int* __restrict__ cursor){
  __shared__ int sp[1024];
  int tid = threadIdx.x;
  int base = tid*8;
  int loc[8]; int s = 0;
  #pragma unroll
  for (int j = 0; j < 8; j++){ loc[j] = degD[base+j]; s += loc[j]; }
  sp[tid] = s; __syncthreads();
  for (int o = 1; o < 1024; o <<= 1){
    int v = (tid >= o) ? sp[tid-o] : 0; __syncthreads();
    sp[tid] += v; __syncthreads();
  }
  int run = sp[tid] - s;   // exclusive
  #pragma unroll
  for (int j = 0; j < 8; j++){ row_ptr[base+j] = run; cursor[base+j] = run; run += loc[j]; }
  if (tid == 1023) row_ptr[NN] = sp[1023];
}

__global__ void k_csr_fill(const int* __restrict__ esrc, const int* __restrict__ edst,
                           int* __restrict__ cursor, int* __restrict__ csr_src){
  int e = blockIdx.x*256 + threadIdx.x;
  if (e < NE_){
    int d = edst[e];
    int p = atomicAdd(&cursor[d], 1);
    csr_src[p] = esrc[e];
  }
}

// ---------------- bf16 MFMA GEMM (128x128 tile, BK=32, 4 waves) ----------------
template<int EPI>
__global__ __launch_bounds__(256) void k_gemm(
    const unsigned short* __restrict__ A, const unsigned short* __restrict__ B,
    int N, int K, int lda, int ldb,
    float* __restrict__ outF, int ldoF,
    unsigned short* __restrict__ outB, int ldoB,
    const float* __restrict__ bias,
    unsigned short* __restrict__ out2)
{
  __shared__ unsigned short sA[128][56];
  __shared__ unsigned short sB[128][56];
  int tid = threadIdx.x;
  int tnc = N >> 7;
  int bm = (blockIdx.x / tnc) << 7;
  int bn = (blockIdx.x % tnc) << 7;
  int wv = tid >> 6, lane = tid & 63;
  int wm = wv >> 1, wn = wv & 1;
  int l15 = lane & 15, l4 = lane >> 4;

  f32x4 acc[4][4];
  #pragma unroll
  for (int i = 0; i < 4; i++)
    #pragma unroll
    for (int j = 0; j < 4; j++)
      acc[i][j] = (f32x4){0.f,0.f,0.f,0.f};

  int r = tid >> 1, hf = tid & 1;
  const unsigned short* gA = A + (size_t)(bm + r)*lda + hf*16;
  const unsigned short* gB = B + (size_t)(bn + r)*ldb + hf*16;

  for (int k0 = 0; k0 < K; k0 += 32){
    short8 va0 = *(const short8*)(gA + k0);
    short8 va1 = *(const short8*)(gA + k0 + 8);
    short8 vb0 = *(const short8*)(gB + k0);
    short8 vb1 = *(const short8*)(gB + k0 + 8);
    __syncthreads();
    *(short8*)&sA[r][hf*16]     = va0;
    *(short8*)&sA[r][hf*16 + 8] = va1;
    *(short8*)&sB[r][hf*16]     = vb0;
    *(short8*)&sB[r][hf*16 + 8] = vb1;
    __syncthreads();
    short8 af[4], bf_[4];
    #pragma unroll
    for (int i = 0; i < 4; i++){
      af[i]  = *(const short8*)&sA[wm*64 + i*16 + l15][l4*8];
      bf_[i] = *(const short8*)&sB[wn*64 + i*16 + l15][l4*8];
    }
    #pragma unroll
    for (int i = 0; i < 4; i++)
      #pragma unroll
      for (int j = 0; j < 4; j++)
        acc[i][j] = __builtin_amdgcn_mfma_f32_16x16x32_bf16(af[i], bf_[j], acc[i][j], 0, 0, 0);
  }

  #pragma unroll
  for (int i = 0; i < 4; i++)
    #pragma unroll
    for (int j = 0; j < 4; j++)
      #pragma unroll
      for (int rr = 0; rr < 4; rr++){
        int row = bm + wm*64 + i*16 + l4*4 + rr;
        int col = bn + wn*64 + j*16 + l15;
        float v = acc[i][j][rr];
        if (EPI == 0){
          outB[(size_t)row*ldoB + col] = f2bf(v);
        } else if (EPI == 1){
          outF[(size_t)row*ldoF + col] = v;
          if (col < 64) out2[(size_t)row*64 + col] = (col < 48) ? f2bf(v) : (unsigned short)0;
        } else if (EPI == 2){
          v += bias[col];
          float sp = (v > 20.f) ? v : log1pf(expf(v));
          outF[(size_t)row*ldoF + col] = sp;
        } else {
          v += bias[col];
          float g = 0.5f*v*(1.f + erff(v*0.70710678118f));
          outB[(size_t)row*ldoB + col] = f2bf(g);
        }
      }
}

// ---------------- causal conv + silu ----------------
__global__ void k_conv_silu(const unsigned short* __restrict__ xz, const float* __restrict__ conv_w,
                            const float* __restrict__ conv_b, unsigned short* __restrict__ u){
  int c = blockIdx.x*256 + threadIdx.x;  // 0..1535
  int t = blockIdx.y;
  float acc = conv_b[c];
  #pragma unroll
  for (int k = 0; k < 4; k++){
    int tt = t - 3 + k;
    if (tt >= 0) acc += bf2f(xz[(size_t)tt*3072 + c]) * conv_w[c*4 + k];
  }
  u[(size_t)t*DIM + c] = f2bf(acc * sigmoidf_(acc));
}

// ---------------- selective scan: chunked parallel, split-state (2 thr/channel) ----------------
// block = 256 thr = 128 channels x 2 halves (8 states each); grid (DIM/128, NCH)
__global__ __launch_bounds__(256) void k_scanA(
    const float* __restrict__ delta, const unsigned short* __restrict__ u,
    const float* __restrict__ dbc, const float* __restrict__ A_log,
    float* __restrict__ hend, float* __restrict__ aprod)
{
  __shared__ float sBC[CL][32];   // [t][0:16]=B, [16:32]=C
  int tid = threadIdx.x;
  int half = tid & 1;
  int c = blockIdx.x*128 + (tid >> 1);
  int s0 = half*8;
  int k = blockIdx.y;
  float al2[8];
  #pragma unroll
  for (int s = 0; s < 8; s++) al2[s] = -expf(A_log[(size_t)c*16 + s0 + s]) * 1.44269504f;
  float h[8];
  #pragma unroll
  for (int s = 0; s < 8; s++) h[s] = 0.f;
  float sdt = 0.f;
  for (int idx = tid; idx < CL*32; idx += 256){
    int t = idx >> 5, j = idx & 31;
    sBC[t][j] = dbc[(size_t)(k*CL + t)*128 + 48 + j];
  }
  __syncthreads();
  const float* dp = delta + (size_t)k*CL*DIM + c;
  const unsigned short* up = u + (size_t)k*CL*DIM + c;
  for (int t = 0; t < CL; t++){
    float dt = dp[t*DIM];
    float uu = bf2f(up[t*DIM]);
    float dtu = dt*uu;
    sdt += dt;
    #pragma unroll
    for (int s = 0; s < 8; s++){
      float dA = exp2f(dt*al2[s]);
      h[s] = h[s]*dA + dtu*sBC[t][s0+s];
    }
  }
  size_t base = ((size_t)k*DIM + c)*16 + s0;
  *(f32x4*)&hend[base]    = (f32x4){h[0],h[1],h[2],h[3]};
  *(f32x4*)&hend[base+4]  = (f32x4){h[4],h[5],h[6],h[7]};
  // prod of exp(dt*a) over chunk == 2^(al2 * sum dt) exactly
  *(f32x4*)&aprod[base]   = (f32x4){exp2f(al2[0]*sdt),exp2f(al2[1]*sdt),exp2f(al2[2]*sdt),exp2f(al2[3]*sdt)};
  *(f32x4*)&aprod[base+4] = (f32x4){exp2f(al2[4]*sdt),exp2f(al2[5]*sdt),exp2f(al2[6]*sdt),exp2f(al2[7]*sdt)};
}

__global__ __launch_bounds__(256) void k_scanB(float* __restrict__ hend, const float* __restrict__ aprod){
  int i = blockIdx.x*256 + threadIdx.x;  // 0..24575 = (c,s) flat
  float H = 0.f;
  for (int k = 0; k < NCH; k++){
    size_t o = (size_t)k*DIM*16 + i;
    float e = hend[o], ap = aprod[o];
    hend[o] = H;          // incoming state for chunk k
    H = e + ap*H;         // exact linear-recurrence composition
  }
}

__global__ __launch_bounds__(256) void k_scanC(
    const float* __restrict__ delta, const unsigned short* __restrict__ u,
    const unsigned short* __restrict__ xz, const float* __restrict__ dbc,
    const float* __restrict__ A_log, const float* __restrict__ D_param,
    const float* __restrict__ hin, unsigned short* __restrict__ y)
{
  __shared__ float sBC[CL][32];
  int tid = threadIdx.x;
  int half = tid & 1;
  int c = blockIdx.x*128 + (tid >> 1);
  int s0 = half*8;
  int k = blockIdx.y;
  float al2[8];
  #pragma unroll
  for (int s = 0; s < 8; s++) al2[s] = -expf(A_log[(size_t)c*16 + s0 + s]) * 1.44269504f;
  float Dc = D_param[c];
  float h[8];
  size_t base = ((size_t)k*DIM + c)*16 + s0;
  {
    f32x4 v0 = *(const f32x4*)&hin[base];
    f32x4 v1 = *(const f32x4*)&hin[base+4];
    h[0]=v0.x; h[1]=v0.y; h[2]=v0.z; h[3]=v0.w;
    h[4]=v1.x; h[5]=v1.y; h[6]=v1.z; h[7]=v1.w;
  }
  for (int idx = tid; idx < CL*32; idx += 256){
    int t = idx >> 5, j = idx & 31;
    sBC[t][j] = dbc[(size_t)(k*CL + t)*128 + 48 + j];
  }
  __syncthreads();
  const float* dp = delta + (size_t)k*CL*DIM + c;
  const unsigned short* up = u + (size_t)k*CL*DIM + c;
  const unsigned short* zp = xz + (size_t)k*CL*3072 + 1536 + c;
  unsigned short* yp = y + (size_t)k*CL*DIM + c;
  for (int t = 0; t < CL; t++){
    float dt = dp[t*DIM];
    float uu = bf2f(up[t*DIM]);
    float dtu = dt*uu;
    float acc = 0.f;
    #pragma unroll
    for (int s = 0; s < 8; s++){
      float dA = exp2f(dt*al2[s]);
      h[s] = h[s]*dA + dtu*sBC[t][s0+s];
      acc += h[s]*sBC[t][16+s0+s];
    }
    acc += __shfl_xor(acc, 1);   // combine the two 8-state halves
    if (half == 0){
      float zz = bf2f(zp[t*3072]);
      float yv = (acc + uu*Dc) * (zz * sigmoidf_(zz));
      yp[t*DIM] = f2bf(yv);
    }
  }
}

// ---------------- GCN aggregation ----------------
__global__ __launch_bounds__(192) void k_aggregate(
    const unsigned short* __restrict__ h, const int* __restrict__ row_ptr,
    const int* __restrict__ csr_src, const float* __restrict__ normS,
    const float* __restrict__ normD, unsigned short* __restrict__ m)
{
  int d = blockIdx.x; int tid = threadIdx.x;
  int e0 = row_ptr[d], e1 = row_ptr[d+1];
  float a0 = 0.f, a1 = 0.f, a2 = 0.f, a3 = 0.f;
  for (int e = e0; e < e1; e++){
    int sI = csr_src[e];
    float ns = normS[sI];
    uint2 v = *((const uint2*)(h + (size_t)sI*DF) + tid);
    a0 += bf2f((unsigned short)(v.x & 0xffff)) * ns;
    a1 += bf2f((unsigned short)(v.x >> 16)) * ns;
    a2 += bf2f((unsigned short)(v.y & 0xffff)) * ns;
    a3 += bf2f((unsigned short)(v.y >> 16)) * ns;
  }
  float nd = normD[d];
  uint2 o;
  o.x = (unsigned int)f2bf(a0*nd) | ((unsigned int)f2bf(a1*nd) << 16);
  o.y = (unsigned int)f2bf(a2*nd) | ((unsigned int)f2bf(a3*nd) << 16);
  *((uint2*)(m + (size_t)d*DF) + tid) = o;
}

// ---------------- finals ----------------
__global__ __launch_bounds__(256) void k_causal(const unsigned short* __restrict__ h,
                                                const float* __restrict__ W_c,
                                                const float* __restrict__ b_c,
                                                float* __restrict__ out){
  int wv = threadIdx.x >> 6, lane = threadIdx.x & 63;
  int r = blockIdx.x*4 + wv;
  float s = 0.f;
  #pragma unroll
  for (int j = 0; j < 12; j++){
    int cidx = lane + 64*j;
    s += bf2f(h[(size_t)r*DF + cidx]) * W_c[cidx];
  }
  s += __shfl_xor(s, 32); s += __shfl_xor(s, 16); s += __shfl_xor(s, 8);
  s += __shfl_xor(s, 4);  s += __shfl_xor(s, 2);  s += __shfl_xor(s, 1);
  if (lane == 0){
    float a = s + b_c[0];
    float cz = sigmoidf_(a);
    out[DF + r] = cz;
    out[DF + NN + r] = (cz > 0.7f) ? 1.f : 0.f;
  }
}

__global__ void k_gfeat(const unsigned short* __restrict__ h, float* __restrict__ out){
  int col = blockIdx.x*256 + threadIdx.x;
  int r0 = blockIdx.y * 512;
  float s = 0.f;
  for (int r = r0; r < r0 + 512; r++) s += bf2f(h[(size_t)r*DF + col]);
  atomicAdd(&out[col], s * (1.f/8192.f));
}

// ---------------- launch ----------------
extern "C" void kernel_launch(void* const* d_in, const int* in_sizes, int n_in,
                              void* d_out, int out_size, void* d_ws, size_t ws_size,
                              hipStream_t stream) {
  const float* node_feats = (const float*)d_in[0];
  const int*   timestamps = (const int*)d_in[1];
  const int*   ei         = (const int*)d_in[2];
  const int*   e_src = ei;
  const int*   e_dst = ei + NE_;
  const float* W_in    = (const float*)d_in[3];
  const float* conv_w  = (const float*)d_in[4];
  const float* conv_b  = (const float*)d_in[5];
  const float* W_xproj = (const float*)d_in[6];
  const float* W_dt    = (const float*)d_in[7];
  const float* b_dt    = (const float*)d_in[8];
  const float* A_log   = (const float*)d_in[9];
  const float* D_param = (const float*)d_in[10];
  const float* W_out   = (const float*)d_in[11];
  const float* Wg      = (const float*)d_in[12];
  const float* bg      = (const float*)d_in[13];
  const float* W_c     = (const float*)d_in[14];
  const float* b_c     = (const float*)d_in[15];
  float* out = (float*)d_out;

  char* ws = (char*)d_ws;
  size_t off = 0;
  auto alloc = [&](size_t bytes) -> char* {
    char* p = ws + off; off += (bytes + 255) & ~(size_t)255; return p;
  };
  unsigned short* WinT   = (unsigned short*)alloc((size_t)3072*768*2);
  unsigned short* WxT    = (unsigned short*)alloc((size_t)128*1536*2);
  unsigned short* WdtT   = (unsigned short*)alloc((size_t)1536*64*2);
  unsigned short* WoutT  = (unsigned short*)alloc((size_t)768*1536*2);
  unsigned short* WgT    = (unsigned short*)alloc((size_t)3*768*768*2);
  unsigned short* seq    = (unsigned short*)alloc((size_t)NN*DF*2);
  unsigned short* xz     = (unsigned short*)alloc((size_t)NN*3072*2);
  unsigned short* ubuf   = (unsigned short*)alloc((size_t)NN*DIM*2);
  float*          dbc    = (float*)alloc((size_t)NN*128*4);
  unsigned short* dt48   = (unsigned short*)alloc((size_t)NN*64*2);
  float*          deltaB = (float*)alloc((size_t)NN*DIM*4);
  unsigned short* ybuf   = (unsigned short*)alloc((size_t)NN*DIM*2);
  unsigned short* hbuf   = (unsigned short*)alloc((size_t)NN*DF*2);
  unsigned short* mbuf   = (unsigned short*)alloc((size_t)NN*DF*2);
  int*   pos    = (int*)alloc((size_t)NN*4);
  int*   degS   = (int*)alloc((size_t)2*NN*4);
  int*   degD   = degS + NN;
  float* normS  = (float*)alloc((size_t)NN*4);
  float* normD  = (float*)alloc((size_t)NN*4);
  int*   rowp   = (int*)alloc((size_t)(NN+1)*4);
  int*   cursor = (int*)alloc((size_t)NN*4);
  int*   csr    = (int*)alloc((size_t)NE_*4);

  // scan chunk summaries (12.58 MB each): hend aliases seq (dead after G1);
  // aprod aliases mbuf (first written by k_aggregate, after the scan)
  float* hend  = (float*)seq;
  float* aprod = (float*)mbuf;

  // zero-init accumulated buffers every call (harness poisons ws/d_out once)
  hipMemsetAsync(degS, 0, (size_t)2*NN*4, stream);
  hipMemsetAsync(pos, 0, (size_t)NN*4, stream);
  hipMemsetAsync(out, 0, (size_t)DF*4, stream);

  // weights: transpose+cast (B operands stored N x K row-major, zero-padded)
  k_transpose_cast<<<dim3(3, 3072), 256, 0, stream>>>(W_in, WinT, 768, 3072, 768);
  k_transpose_cast<<<dim3(6, 128),  256, 0, stream>>>(W_xproj, WxT, 1536, 80, 1536);
  k_transpose_cast<<<dim3(1, 1536), 256, 0, stream>>>(W_dt, WdtT, 48, 1536, 64);
  k_transpose_cast<<<dim3(6, 768),  256, 0, stream>>>(W_out, WoutT, 1536, 768, 1536);
  for (int i = 0; i < 3; i++)
    k_transpose_cast<<<dim3(3, 768), 256, 0, stream>>>(Wg + (size_t)i*768*768, WgT + (size_t)i*768*768, 768, 768, 768);

  // sort + gather (rank 2D-parallel: 32x32 blocks)
  k_rank<<<dim3(NN/256, NN/256), 256, 0, stream>>>(timestamps, pos);
  k_gather<<<NN, 256, 0, stream>>>(node_feats, pos, seq);

  // graph structure
  k_deg_count<<<NE_/256, 256, 0, stream>>>(e_src, e_dst, degS, degD);
  k_norms<<<NN/256, 256, 0, stream>>>(degS, degD, normS, normD);
  k_rowptr<<<1, 1024, 0, stream>>>(degD, rowp, cursor);
  k_csr_fill<<<NE_/256, 256, 0, stream>>>(e_src, e_dst, cursor, csr);

  // G1: xz = seq @ W_in  (8192x3072, K=768)
  k_gemm<0><<<64*24, 256, 0, stream>>>(seq, WinT, 3072, 768, 768, 768,
                                       nullptr, 0, xz, 3072, nullptr, nullptr);
  // conv + silu -> u
  k_conv_silu<<<dim3(6, NN), 256, 0, stream>>>(xz, conv_w, conv_b, ubuf);
  // G2: dbc = u @ W_xproj  (8192x128pad, K=1536); also dt48 bf16 (cols<48)
  k_gemm<1><<<64*1, 256, 0, stream>>>(ubuf, WxT, 128, 1536, 1536, 1536,
                                      dbc, 128, nullptr, 0, nullptr, dt48);
  // G3: delta = softplus(dt48 @ W_dt + b_dt)  (8192x1536, K=64)
  k_gemm<2><<<64*12, 256, 0, stream>>>(dt48, WdtT, 1536, 64, 64, 64,
                                       deltaB, 1536, nullptr, 0, b_dt, nullptr);
  // chunked scan -> y (fused (y + u*D)*silu(z)); split-state grids
  k_scanA<<<dim3(DIM/128, NCH), 256, 0, stream>>>(deltaB, ubuf, dbc, A_log, hend, aprod);
  k_scanB<<<96, 256, 0, stream>>>(hend, aprod);
  k_scanC<<<dim3(DIM/128, NCH), 256, 0, stream>>>(deltaB, ubuf, xz, dbc, A_log, D_param, hend, ybuf);
  // G4: h = y @ W_out  (8192x768, K=1536)
  k_gemm<0><<<64*6, 256, 0, stream>>>(ybuf, WoutT, 768, 1536, 1536, 1536,
                                      nullptr, 0, hbuf, 768, nullptr, nullptr);
  // 3 GCN layers
  for (int i = 0; i < 3; i++){
    k_aggregate<<<NN, 192, 0, stream>>>(hbuf, rowp, csr, normS, normD, mbuf);
    k_gemm<3><<<64*6, 256, 0, stream>>>(mbuf, WgT + (size_t)i*768*768, 768, 768, 768, 768,
                                        nullptr, 0, hbuf, 768, bg + (size_t)i*768, nullptr);
  }
  // finals
  k_causal<<<NN/4, 256, 0, stream>>>(hbuf, W_c, b_c, out);
  k_gfeat<<<dim3(3, 16), 256, 0, stream>>>(hbuf, out);
}

// Round 11
// 800.175 us; speedup vs baseline: 1.0572x; 1.0572x over previous
//
#include <hip/hip_runtime.h>
#include <math.h>

#define NN 8192
#define DF 768
#define NE_ 262144
#define DIM 1536
#define DSN 16
#define NCH 128
#define CL  64   // NN / NCH

typedef short short8 __attribute__((ext_vector_type(8)));
typedef float f32x4 __attribute__((ext_vector_type(4)));

__device__ __forceinline__ float bf2f(unsigned short u){
  unsigned int v = ((unsigned int)u) << 16; float f; __builtin_memcpy(&f, &v, 4); return f;
}
__device__ __forceinline__ unsigned short f2bf(float f){
  unsigned int x; __builtin_memcpy(&x, &f, 4);
  x += 0x7fffu + ((x >> 16) & 1u);
  return (unsigned short)(x >> 16);
}
__device__ __forceinline__ float sigmoidf_(float x){ return 1.f/(1.f+expf(-x)); }
#define EXP2RAW(x) __builtin_amdgcn_exp2f(x)   // single v_exp_f32
#define LOG2E 1.44269504088896f

// ---------------- prep kernels ----------------

__global__ void k_transpose_cast(const float* __restrict__ in, unsigned short* __restrict__ out,
                                 int K, int N, int Kp){
  int k = blockIdx.x*256 + threadIdx.x;
  int n = blockIdx.y;
  if (k >= Kp) return;
  unsigned short v = 0;
  if (k < K && n < N) v = f2bf(in[(size_t)k*N + n]);
  out[(size_t)n*Kp + k] = v;
}

// stable rank, 2D-parallel
__global__ __launch_bounds__(256) void k_rank(const int* __restrict__ ts, int* __restrict__ pos){
  __shared__ int sT[256];
  int i = blockIdx.x*256 + threadIdx.x;
  int my = ts[i];
  int c0 = blockIdx.y*256;
  sT[threadIdx.x] = ts[c0 + threadIdx.x];
  __syncthreads();
  int r = 0;
  #pragma unroll 8
  for (int j = 0; j < 256; j++){
    int t = sT[j]; int jj = c0 + j;
    r += (t < my || (t == my && jj < i)) ? 1 : 0;
  }
  atomicAdd(&pos[i], r);
}

__global__ void k_gather(const float* __restrict__ nf, const int* __restrict__ pos,
                         unsigned short* __restrict__ seq){
  int i = blockIdx.x; int p = pos[i];
  const float* src = nf + (size_t)i*DF;
  unsigned short* dst = seq + (size_t)p*DF;
  for (int j = threadIdx.x; j < DF; j += 256) dst[j] = f2bf(src[j]);
}

__global__ void k_deg_count(const int* __restrict__ esrc, const int* __restrict__ edst,
                            int* __restrict__ degS, int* __restrict__ degD){
  int e = blockIdx.x*256 + threadIdx.x;
  if (e < NE_){ atomicAdd(&degS[esrc[e]], 1); atomicAdd(&degD[edst[e]], 1); }
}

__global__ void k_norms(const int* __restrict__ degS, const int* __restrict__ degD,
                        float* __restrict__ normS, float* __restrict__ normD){
  int i = blockIdx.x*256 + threadIdx.x;
  if (i < NN){
    normS[i] = rsqrtf(fmaxf((float)degS[i], 1.f));
    normD[i] = rsqrtf(fmaxf((float)degD[i], 1.f));
  }
}

__global__ __launch_bounds__(1024) void k_rowptr(const int* __restrict__ degD,
                                                 int* __restrict__ row_ptr, int* __restrict__ cursor){
  __shared__ int sp[1024];
  int tid = threadIdx.x;
  int base = tid*8;
  int loc[8]; int s = 0;
  #pragma unroll
  for (int j = 0; j < 8; j++){ loc[j] = degD[base+j]; s += loc[j]; }
  sp[tid] = s; __syncthreads();
  for (int o = 1; o < 1024; o <<= 1){
    int v = (tid >= o) ? sp[tid-o] : 0; __syncthreads();
    sp[tid] += v; __syncthreads();
  }
  int run = sp[tid] - s;   // exclusive
  #pragma unroll
  for (int j = 0; j < 8; j++){ row_ptr[base+j] = run; cursor[base+j] = run; run += loc[j]; }
  if (tid == 1023) row_ptr[NN] = sp[1023];
}

__global__ void k_csr_fill(const int* __restrict__ esrc, const int* __restrict__ edst,
                           int* __restrict__ cursor, int* __restrict__ csr_src){
  int e = blockIdx.x*256 + threadIdx.x;
  if (e < NE_){
    int d = edst[e];
    int p = atomicAdd(&cursor[d], 1);
    csr_src[p] = esrc[e];
  }
}

// ---------------- bf16 MFMA GEMM (128x128 tile, BK=32, 4 waves) ----------------
template<int EPI>
__global__ __launch_bounds__(256) void k_gemm(
    const unsigned short* __restrict__ A, const unsigned short* __restrict__ B,
    int N, int K, int lda, int ldb,
    float* __restrict__ outF, int ldoF,
    unsigned short* __restrict__ outB, int ldoB,
    const float* __restrict__ bias,
    unsigned short* __restrict__ out2)
{
  __shared__ unsigned short sA[128][56];
  __shared__ unsigned short sB[128][56];
  int tid = threadIdx.x;
  int tnc = N >> 7;
  int bm = (blockIdx.x / tnc) << 7;
  int bn = (blockIdx.x % tnc) << 7;
  int wv = tid >> 6, lane = tid & 63;
  int wm = wv >> 1, wn = wv & 1;
  int l15 = lane & 15, l4 = lane >> 4;

  f32x4 acc[4][4];
  #pragma unroll
  for (int i = 0; i < 4; i++)
    #pragma unroll
    for (int j = 0; j < 4; j++)
      acc[i][j] = (f32x4){0.f,0.f,0.f,0.f};

  int r = tid >> 1, hf = tid & 1;
  const unsigned short* gA = A + (size_t)(bm + r)*lda + hf*16;
  const unsigned short* gB = B + (size_t)(bn + r)*ldb + hf*16;

  for (int k0 = 0; k0 < K; k0 += 32){
    short8 va0 = *(const short8*)(gA + k0);
    short8 va1 = *(const short8*)(gA + k0 + 8);
    short8 vb0 = *(const short8*)(gB + k0);
    short8 vb1 = *(const short8*)(gB + k0 + 8);
    __syncthreads();
    *(short8*)&sA[r][hf*16]     = va0;
    *(short8*)&sA[r][hf*16 + 8] = va1;
    *(short8*)&sB[r][hf*16]     = vb0;
    *(short8*)&sB[r][hf*16 + 8] = vb1;
    __syncthreads();
    short8 af[4], bf_[4];
    #pragma unroll
    for (int i = 0; i < 4; i++){
      af[i]  = *(const short8*)&sA[wm*64 + i*16 + l15][l4*8];
      bf_[i] = *(const short8*)&sB[wn*64 + i*16 + l15][l4*8];
    }
    #pragma unroll
    for (int i = 0; i < 4; i++)
      #pragma unroll
      for (int j = 0; j < 4; j++)
        acc[i][j] = __builtin_amdgcn_mfma_f32_16x16x32_bf16(af[i], bf_[j], acc[i][j], 0, 0, 0);
  }

  #pragma unroll
  for (int i = 0; i < 4; i++)
    #pragma unroll
    for (int j = 0; j < 4; j++)
      #pragma unroll
      for (int rr = 0; rr < 4; rr++){
        int row = bm + wm*64 + i*16 + l4*4 + rr;
        int col = bn + wn*64 + j*16 + l15;
        float v = acc[i][j][rr];
        if (EPI == 0){
          outB[(size_t)row*ldoB + col] = f2bf(v);
        } else if (EPI == 1){
          outF[(size_t)row*ldoF + col] = v;
          if (col < 64) out2[(size_t)row*64 + col] = (col < 48) ? f2bf(v) : (unsigned short)0;
        } else if (EPI == 2){
          v += bias[col];
          float sp = (v > 20.f) ? v : log1pf(expf(v));
          outF[(size_t)row*ldoF + col] = sp;
        } else {
          v += bias[col];
          float g = 0.5f*v*(1.f + erff(v*0.70710678118f));
          outB[(size_t)row*ldoB + col] = f2bf(g);
        }
      }
}

// ---------------- causal conv + silu ----------------
__global__ void k_conv_silu(const unsigned short* __restrict__ xz, const float* __restrict__ conv_w,
                            const float* __restrict__ conv_b, unsigned short* __restrict__ u){
  int c = blockIdx.x*256 + threadIdx.x;  // 0..1535
  int t = blockIdx.y;
  float acc = conv_b[c];
  #pragma unroll
  for (int k = 0; k < 4; k++){
    int tt = t - 3 + k;
    if (tt >= 0) acc += bf2f(xz[(size_t)tt*3072 + c]) * conv_w[c*4 + k];
  }
  u[(size_t)t*DIM + c] = f2bf(acc * sigmoidf_(acc));
}

// ---------------- selective scan: chunked parallel (R8 structure + native exp2) ----------------
// thread = channel (16 states in registers); grid (DIM/256, NCH)
__global__ __launch_bounds__(256) void k_scanA(
    const float* __restrict__ delta, const unsigned short* __restrict__ u,
    const float* __restrict__ dbc, const float* __restrict__ A_log,
    float* __restrict__ hend, float* __restrict__ aprod)
{
  __shared__ float sBC[CL][32];   // [t][0:16]=B, [16:32]=C
  int tid = threadIdx.x;
  int c = blockIdx.x*256 + tid;
  int k = blockIdx.y;
  float al2[16];
  #pragma unroll
  for (int s = 0; s < 16; s++) al2[s] = -expf(A_log[(size_t)c*16 + s]) * LOG2E;
  float h[16];
  #pragma unroll
  for (int s = 0; s < 16; s++) h[s] = 0.f;
  float sdt = 0.f;
  for (int idx = tid; idx < CL*32; idx += 256){
    int t = idx >> 5, j = idx & 31;
    sBC[t][j] = dbc[(size_t)(k*CL + t)*128 + 48 + j];
  }
  __syncthreads();
  const float* dp = delta + (size_t)k*CL*DIM + c;
  const unsigned short* up = u + (size_t)k*CL*DIM + c;
  for (int t = 0; t < CL; t++){
    float dt = dp[t*DIM];
    float uu = bf2f(up[t*DIM]);
    float dtu = dt*uu;
    sdt += dt;
    #pragma unroll
    for (int s = 0; s < 16; s++){
      float dA = EXP2RAW(dt*al2[s]);
      h[s] = h[s]*dA + dtu*sBC[t][s];
    }
  }
  size_t base = ((size_t)k*DIM + c)*16;
  #pragma unroll
  for (int s = 0; s < 16; s += 4){
    *(f32x4*)&hend[base+s]  = (f32x4){h[s],h[s+1],h[s+2],h[s+3]};
    // prod over chunk of exp(dt*a) == 2^(al2 * sum dt) exactly
    *(f32x4*)&aprod[base+s] = (f32x4){EXP2RAW(al2[s]*sdt),EXP2RAW(al2[s+1]*sdt),
                                      EXP2RAW(al2[s+2]*sdt),EXP2RAW(al2[s+3]*sdt)};
  }
}

__global__ __launch_bounds__(256) void k_scanB(float* __restrict__ hend, const float* __restrict__ aprod){
  int i = blockIdx.x*256 + threadIdx.x;  // 0..24575 = (c,s) flat
  float H = 0.f;
  for (int k = 0; k < NCH; k++){
    size_t o = (size_t)k*DIM*16 + i;
    float e = hend[o], ap = aprod[o];
    hend[o] = H;          // incoming state for chunk k
    H = e + ap*H;         // exact linear-recurrence composition
  }
}

__global__ __launch_bounds__(256) void k_scanC(
    const float* __restrict__ delta, const unsigned short* __restrict__ u,
    const unsigned short* __restrict__ xz, const float* __restrict__ dbc,
    const float* __restrict__ A_log, const float* __restrict__ D_param,
    const float* __restrict__ hin, unsigned short* __restrict__ y)
{
  __shared__ float sBC[CL][32];
  int tid = threadIdx.x;
  int c = blockIdx.x*256 + tid;
  int k = blockIdx.y;
  float al2[16];
  #pragma unroll
  for (int s = 0; s < 16; s++) al2[s] = -expf(A_log[(size_t)c*16 + s]) * LOG2E;
  float Dc = D_param[c];
  float h[16];
  size_t base = ((size_t)k*DIM + c)*16;
  #pragma unroll
  for (int s = 0; s < 16; s += 4){
    f32x4 v = *(const f32x4*)&hin[base+s];
    h[s] = v.x; h[s+1] = v.y; h[s+2] = v.z; h[s+3] = v.w;
  }
  for (int idx = tid; idx < CL*32; idx += 256){
    int t = idx >> 5, j = idx & 31;
    sBC[t][j] = dbc[(size_t)(k*CL + t)*128 + 48 + j];
  }
  __syncthreads();
  const float* dp = delta + (size_t)k*CL*DIM + c;
  const unsigned short* up = u + (size_t)k*CL*DIM + c;
  const unsigned short* zp = xz + (size_t)k*CL*3072 + 1536 + c;
  unsigned short* yp = y + (size_t)k*CL*DIM + c;
  for (int t = 0; t < CL; t++){
    float dt = dp[t*DIM];
    float uu = bf2f(up[t*DIM]);
    float zz = bf2f(zp[t*3072]);
    float dtu = dt*uu;
    float acc = 0.f;
    #pragma unroll
    for (int s = 0; s < 16; s++){
      float dA = EXP2RAW(dt*al2[s]);
      h[s] = h[s]*dA + dtu*sBC[t][s];
      acc += h[s]*sBC[t][16+s];
    }
    float yv = (acc + uu*Dc) * (zz * sigmoidf_(zz));
    yp[t*DIM] = f2bf(yv);
  }
}

// ---------------- GCN aggregation ----------------
__global__ __launch_bounds__(192) void k_aggregate(
    const unsigned short* __restrict__ h, const int* __restrict__ row_ptr,
    const int* __restrict__ csr_src, const float* __restrict__ normS,
    const float* __restrict__ normD, unsigned short* __restrict__ m)
{
  int d = blockIdx.x; int tid = threadIdx.x;
  int e0 = row_ptr[d], e1 = row_ptr[d+1];
  float a0 = 0.f, a1 = 0.f, a2 = 0.f, a3 = 0.f;
  for (int e = e0; e < e1; e++){
    int sI = csr_src[e];
    float ns = normS[sI];
    uint2 v = *((const uint2*)(h + (size_t)sI*DF) + tid);
    a0 += bf2f((unsigned short)(v.x & 0xffff)) * ns;
    a1 += bf2f((unsigned short)(v.x >> 16)) * ns;
    a2 += bf2f((unsigned short)(v.y & 0xffff)) * ns;
    a3 += bf2f((unsigned short)(v.y >> 16)) * ns;
  }
  float nd = normD[d];
  uint2 o;
  o.x = (unsigned int)f2bf(a0*nd) | ((unsigned int)f2bf(a1*nd) << 16);
  o.y = (unsigned int)f2bf(a2*nd) | ((unsigned int)f2bf(a3*nd) << 16);
  *((uint2*)(m + (size_t)d*DF) + tid) = o;
}

// ---------------- finals ----------------
__global__ __launch_bounds__(256) void k_causal(const unsigned short* __restrict__ h,
                                                const float* __restrict__ W_c,
                                                const float* __restrict__ b_c,
                                                float* __restrict__ out){
  int wv = threadIdx.x >> 6, lane = threadIdx.x & 63;
  int r = blockIdx.x*4 + wv;
  float s = 0.f;
  #pragma unroll
  for (int j = 0; j < 12; j++){
    int cidx = lane + 64*j;
    s += bf2f(h[(size_t)r*DF + cidx]) * W_c[cidx];
  }
  s += __shfl_xor(s, 32); s += __shfl_xor(s, 16); s += __shfl_xor(s, 8);
  s += __shfl_xor(s, 4);  s += __shfl_xor(s, 2);  s += __shfl_xor(s, 1);
  if (lane == 0){
    float a = s + b_c[0];
    float cz = sigmoidf_(a);
    out[DF + r] = cz;
    out[DF + NN + r] = (cz > 0.7f) ? 1.f : 0.f;
  }
}

__global__ void k_gfeat(const unsigned short* __restrict__ h, float* __restrict__ out){
  int col = blockIdx.x*256 + threadIdx.x;
  int r0 = blockIdx.y * 512;
  float s = 0.f;
  for (int r = r0; r < r0 + 512; r++) s += bf2f(h[(size_t)r*DF + col]);
  atomicAdd(&out[col], s * (1.f/8192.f));
}

// ---------------- launch ----------------
extern "C" void kernel_launch(void* const* d_in, const int* in_sizes, int n_in,
                              void* d_out, int out_size, void* d_ws, size_t ws_size,
                              hipStream_t stream) {
  const float* node_feats = (const float*)d_in[0];
  const int*   timestamps = (const int*)d_in[1];
  const int*   ei         = (const int*)d_in[2];
  const int*   e_src = ei;
  const int*   e_dst = ei + NE_;
  const float* W_in    = (const float*)d_in[3];
  const float* conv_w  = (const float*)d_in[4];
  const float* conv_b  = (const float*)d_in[5];
  const float* W_xproj = (const float*)d_in[6];
  const float* W_dt    = (const float*)d_in[7];
  const float* b_dt    = (const float*)d_in[8];
  const float* A_log   = (const float*)d_in[9];
  const float* D_param = (const float*)d_in[10];
  const float* W_out   = (const float*)d_in[11];
  const float* Wg      = (const float*)d_in[12];
  const float* bg      = (const float*)d_in[13];
  const float* W_c     = (const float*)d_in[14];
  const float* b_c     = (const float*)d_in[15];
  float* out = (float*)d_out;

  char* ws = (char*)d_ws;
  size_t off = 0;
  auto alloc = [&](size_t bytes) -> char* {
    char* p = ws + off; off += (bytes + 255) & ~(size_t)255; return p;
  };
  unsigned short* WinT   = (unsigned short*)alloc((size_t)3072*768*2);
  unsigned short* WxT    = (unsigned short*)alloc((size_t)128*1536*2);
  unsigned short* WdtT   = (unsigned short*)alloc((size_t)1536*64*2);
  unsigned short* WoutT  = (unsigned short*)alloc((size_t)768*1536*2);
  unsigned short* WgT    = (unsigned short*)alloc((size_t)3*768*768*2);
  unsigned short* seq    = (unsigned short*)alloc((size_t)NN*DF*2);
  unsigned short* xz     = (unsigned short*)alloc((size_t)NN*3072*2);
  unsigned short* ubuf   = (unsigned short*)alloc((size_t)NN*DIM*2);
  float*          dbc    = (float*)alloc((size_t)NN*128*4);
  unsigned short* dt48   = (unsigned short*)alloc((size_t)NN*64*2);
  float*          deltaB = (float*)alloc((size_t)NN*DIM*4);
  unsigned short* ybuf   = (unsigned short*)alloc((size_t)NN*DIM*2);
  unsigned short* hbuf   = (unsigned short*)alloc((size_t)NN*DF*2);
  unsigned short* mbuf   = (unsigned short*)alloc((size_t)NN*DF*2);
  int*   pos    = (int*)alloc((size_t)NN*4);
  int*   degS   = (int*)alloc((size_t)2*NN*4);
  int*   degD   = degS + NN;
  float* normS  = (float*)alloc((size_t)NN*4);
  float* normD  = (float*)alloc((size_t)NN*4);
  int*   rowp   = (int*)alloc((size_t)(NN+1)*4);
  int*   cursor = (int*)alloc((size_t)NN*4);
  int*   csr    = (int*)alloc((size_t)NE_*4);

  // scan chunk summaries (12.58 MB each): hend aliases seq (dead after G1);
  // aprod aliases mbuf (first written by k_aggregate, after the scan)
  float* hend  = (float*)seq;
  float* aprod = (float*)mbuf;

  // zero-init accumulated buffers every call (harness poisons ws/d_out once)
  hipMemsetAsync(degS, 0, (size_t)2*NN*4, stream);
  hipMemsetAsync(pos, 0, (size_t)NN*4, stream);
  hipMemsetAsync(out, 0, (size_t)DF*4, stream);

  // weights: transpose+cast (B operands stored N x K row-major, zero-padded)
  k_transpose_cast<<<dim3(3, 3072), 256, 0, stream>>>(W_in, WinT, 768, 3072, 768);
  k_transpose_cast<<<dim3(6, 128),  256, 0, stream>>>(W_xproj, WxT, 1536, 80, 1536);
  k_transpose_cast<<<dim3(1, 1536), 256, 0, stream>>>(W_dt, WdtT, 48, 1536, 64);
  k_transpose_cast<<<dim3(6, 768),  256, 0, stream>>>(W_out, WoutT, 1536, 768, 1536);
  for (int i = 0; i < 3; i++)
    k_transpose_cast<<<dim3(3, 768), 256, 0, stream>>>(Wg + (size_t)i*768*768, WgT + (size_t)i*768*768, 768, 768, 768);

  // sort + gather (rank 2D-parallel: 32x32 blocks)
  k_rank<<<dim3(NN/256, NN/256), 256, 0, stream>>>(timestamps, pos);
  k_gather<<<NN, 256, 0, stream>>>(node_feats, pos, seq);

  // graph structure
  k_deg_count<<<NE_/256, 256, 0, stream>>>(e_src, e_dst, degS, degD);
  k_norms<<<NN/256, 256, 0, stream>>>(degS, degD, normS, normD);
  k_rowptr<<<1, 1024, 0, stream>>>(degD, rowp, cursor);
  k_csr_fill<<<NE_/256, 256, 0, stream>>>(e_src, e_dst, cursor, csr);

  // G1: xz = seq @ W_in  (8192x3072, K=768)
  k_gemm<0><<<64*24, 256, 0, stream>>>(seq, WinT, 3072, 768, 768, 768,
                                       nullptr, 0, xz, 3072, nullptr, nullptr);
  // conv + silu -> u
  k_conv_silu<<<dim3(6, NN), 256, 0, stream>>>(xz, conv_w, conv_b, ubuf);
  // G2: dbc = u @ W_xproj  (8192x128pad, K=1536); also dt48 bf16 (cols<48)
  k_gemm<1><<<64*1, 256, 0, stream>>>(ubuf, WxT, 128, 1536, 1536, 1536,
                                      dbc, 128, nullptr, 0, nullptr, dt48);
  // G3: delta = softplus(dt48 @ W_dt + b_dt)  (8192x1536, K=64)
  k_gemm<2><<<64*12, 256, 0, stream>>>(dt48, WdtT, 1536, 64, 64, 64,
                                       deltaB, 1536, nullptr, 0, b_dt, nullptr);
  // chunked scan -> y (fused (y + u*D)*silu(z))
  k_scanA<<<dim3(DIM/256, NCH), 256, 0, stream>>>(deltaB, ubuf, dbc, A_log, hend, aprod);
  k_scanB<<<96, 256, 0, stream>>>(hend, aprod);
  k_scanC<<<dim3(DIM/256, NCH), 256, 0, stream>>>(deltaB, ubuf, xz, dbc, A_log, D_param, hend, ybuf);
  // G4: h = y @ W_out  (8192x768, K=1536)
  k_gemm<0><<<64*6, 256, 0, stream>>>(ybuf, WoutT, 768, 1536, 1536, 1536,
                                      nullptr, 0, hbuf, 768, nullptr, nullptr);
  // 3 GCN layers
  for (int i = 0; i < 3; i++){
    k_aggregate<<<NN, 192, 0, stream>>>(hbuf, rowp, csr, normS, normD, mbuf);
    k_gemm<3><<<64*6, 256, 0, stream>>>(mbuf, WgT + (size_t)i*768*768, 768, 768, 768, 768,
                                        nullptr, 0, hbuf, 768, bg + (size_t)i*768, nullptr);
  }
  // finals
  k_causal<<<NN/4, 256, 0, stream>>>(hbuf, W_c, b_c, out);
  k_gfeat<<<dim3(3, 16), 256, 0, stream>>>(hbuf, out);
}

// Round 12
// 773.431 us; speedup vs baseline: 1.0938x; 1.0346x over previous
//
#include <hip/hip_runtime.h>
#include <math.h>

#define NN 8192
#define DF 768
#define NE_ 262144
#define DIM 1536
#define DSN 16
#define NCH 128
#define CL  64   // NN / NCH

typedef short short8 __attribute__((ext_vector_type(8)));
typedef float f32x4 __attribute__((ext_vector_type(4)));

__device__ __forceinline__ float bf2f(unsigned short u){
  unsigned int v = ((unsigned int)u) << 16; float f; __builtin_memcpy(&f, &v, 4); return f;
}
__device__ __forceinline__ unsigned short f2bf(float f){
  unsigned int x; __builtin_memcpy(&x, &f, 4);
  x += 0x7fffu + ((x >> 16) & 1u);
  return (unsigned short)(x >> 16);
}
__device__ __forceinline__ float sigmoidf_(float x){ return 1.f/(1.f+expf(-x)); }
#define EXP2RAW(x) __builtin_amdgcn_exp2f(x)   // single v_exp_f32
#define LOG2E 1.44269504088896f

// ---------------- prep kernels ----------------

__global__ void k_transpose_cast(const float* __restrict__ in, unsigned short* __restrict__ out,
                                 int K, int N, int Kp){
  int k = blockIdx.x*256 + threadIdx.x;
  int n = blockIdx.y;
  if (k >= Kp) return;
  unsigned short v = 0;
  if (k < K && n < N) v = f2bf(in[(size_t)k*N + n]);
  out[(size_t)n*Kp + k] = v;
}

// stable rank, 2D-parallel
__global__ __launch_bounds__(256) void k_rank(const int* __restrict__ ts, int* __restrict__ pos){
  __shared__ int sT[256];
  int i = blockIdx.x*256 + threadIdx.x;
  int my = ts[i];
  int c0 = blockIdx.y*256;
  sT[threadIdx.x] = ts[c0 + threadIdx.x];
  __syncthreads();
  int r = 0;
  #pragma unroll 8
  for (int j = 0; j < 256; j++){
    int t = sT[j]; int jj = c0 + j;
    r += (t < my || (t == my && jj < i)) ? 1 : 0;
  }
  atomicAdd(&pos[i], r);
}

__global__ void k_gather(const float* __restrict__ nf, const int* __restrict__ pos,
                         unsigned short* __restrict__ seq){
  int i = blockIdx.x; int p = pos[i];
  const float* src = nf + (size_t)i*DF;
  unsigned short* dst = seq + (size_t)p*DF;
  for (int j = threadIdx.x; j < DF; j += 256) dst[j] = f2bf(src[j]);
}

__global__ void k_deg_count(const int* __restrict__ esrc, const int* __restrict__ edst,
                            int* __restrict__ degS, int* __restrict__ degD){
  int e = blockIdx.x*256 + threadIdx.x;
  if (e < NE_){ atomicAdd(&degS[esrc[e]], 1); atomicAdd(&degD[edst[e]], 1); }
}

__global__ void k_norms(const int* __restrict__ degS, const int* __restrict__ degD,
                        float* __restrict__ normS, float* __restrict__ normD){
  int i = blockIdx.x*256 + threadIdx.x;
  if (i < NN){
    normS[i] = rsqrtf(fmaxf((float)degS[i], 1.f));
    normD[i] = rsqrtf(fmaxf((float)degD[i], 1.f));
  }
}

__global__ __launch_bounds__(1024) void k_rowptr(const int* __restrict__ degD,
                                                 int* __restrict__ row_ptr, int* __restrict__ cursor){
  __shared__ int sp[1024];
  int tid = threadIdx.x;
  int base = tid*8;
  int loc[8]; int s = 0;
  #pragma unroll
  for (int j = 0; j < 8; j++){ loc[j] = degD[base+j]; s += loc[j]; }
  sp[tid] = s; __syncthreads();
  for (int o = 1; o < 1024; o <<= 1){
    int v = (tid >= o) ? sp[tid-o] : 0; __syncthreads();
    sp[tid] += v; __syncthreads();
  }
  int run = sp[tid] - s;   // exclusive
  #pragma unroll
  for (int j = 0; j < 8; j++){ row_ptr[base+j] = run; cursor[base+j] = run; run += loc[j]; }
  if (tid == 1023) row_ptr[NN] = sp[1023];
}

__global__ void k_csr_fill(const int* __restrict__ esrc, const int* __restrict__ edst,
                           int* __restrict__ cursor, int* __restrict__ csr_src){
  int e = blockIdx.x*256 + threadIdx.x;
  if (e < NE_){
    int d = edst[e];
    int p = atomicAdd(&cursor[d], 1);
    csr_src[p] = esrc[e];
  }
}

// ---------------- bf16 MFMA GEMM (128x128 tile, BK=32, 4 waves) ----------------
template<int EPI>
__global__ __launch_bounds__(256) void k_gemm(
    const unsigned short* __restrict__ A, const unsigned short* __restrict__ B,
    int N, int K, int lda, int ldb,
    float* __restrict__ outF, int ldoF,
    unsigned short* __restrict__ outB, int ldoB,
    const float* __restrict__ bias,
    unsigned short* __restrict__ out2)
{
  __shared__ unsigned short sA[128][56];
  __shared__ unsigned short sB[128][56];
  int tid = threadIdx.x;
  int tnc = N >> 7;
  int bm = (blockIdx.x / tnc) << 7;
  int bn = (blockIdx.x % tnc) << 7;
  int wv = tid >> 6, lane = tid & 63;
  int wm = wv >> 1, wn = wv & 1;
  int l15 = lane & 15, l4 = lane >> 4;

  f32x4 acc[4][4];
  #pragma unroll
  for (int i = 0; i < 4; i++)
    #pragma unroll
    for (int j = 0; j < 4; j++)
      acc[i][j] = (f32x4){0.f,0.f,0.f,0.f};

  int r = tid >> 1, hf = tid & 1;
  const unsigned short* gA = A + (size_t)(bm + r)*lda + hf*16;
  const unsigned short* gB = B + (size_t)(bn + r)*ldb + hf*16;

  for (int k0 = 0; k0 < K; k0 += 32){
    short8 va0 = *(const short8*)(gA + k0);
    short8 va1 = *(const short8*)(gA + k0 + 8);
    short8 vb0 = *(const short8*)(gB + k0);
    short8 vb1 = *(const short8*)(gB + k0 + 8);
    __syncthreads();
    *(short8*)&sA[r][hf*16]     = va0;
    *(short8*)&sA[r][hf*16 + 8] = va1;
    *(short8*)&sB[r][hf*16]     = vb0;
    *(short8*)&sB[r][hf*16 + 8] = vb1;
    __syncthreads();
    short8 af[4], bf_[4];
    #pragma unroll
    for (int i = 0; i < 4; i++){
      af[i]  = *(const short8*)&sA[wm*64 + i*16 + l15][l4*8];
      bf_[i] = *(const short8*)&sB[wn*64 + i*16 + l15][l4*8];
    }
    #pragma unroll
    for (int i = 0; i < 4; i++)
      #pragma unroll
      for (int j = 0; j < 4; j++)
        acc[i][j] = __builtin_amdgcn_mfma_f32_16x16x32_bf16(af[i], bf_[j], acc[i][j], 0, 0, 0);
  }

  #pragma unroll
  for (int i = 0; i < 4; i++)
    #pragma unroll
    for (int j = 0; j < 4; j++)
      #pragma unroll
      for (int rr = 0; rr < 4; rr++){
        int row = bm + wm*64 + i*16 + l4*4 + rr;
        int col = bn + wn*64 + j*16 + l15;
        float v = acc[i][j][rr];
        if (EPI == 0){
          outB[(size_t)row*ldoB + col] = f2bf(v);
        } else if (EPI == 1){
          outF[(size_t)row*ldoF + col] = v;
          if (col < 64) out2[(size_t)row*64 + col] = (col < 48) ? f2bf(v) : (unsigned short)0;
        } else if (EPI == 2){
          v += bias[col];
          float sp = (v > 20.f) ? v : log1pf(expf(v));
          outF[(size_t)row*ldoF + col] = sp;
        } else {
          v += bias[col];
          float g = 0.5f*v*(1.f + erff(v*0.70710678118f));
          outB[(size_t)row*ldoB + col] = f2bf(g);
        }
      }
}

// ---------------- causal conv + silu ----------------
__global__ void k_conv_silu(const unsigned short* __restrict__ xz, const float* __restrict__ conv_w,
                            const float* __restrict__ conv_b, unsigned short* __restrict__ u){
  int c = blockIdx.x*256 + threadIdx.x;  // 0..1535
  int t = blockIdx.y;
  float acc = conv_b[c];
  #pragma unroll
  for (int k = 0; k < 4; k++){
    int tt = t - 3 + k;
    if (tt >= 0) acc += bf2f(xz[(size_t)tt*3072 + c]) * conv_w[c*4 + k];
  }
  u[(size_t)t*DIM + c] = f2bf(acc * sigmoidf_(acc));
}

// ---------------- selective scan: chunked parallel + power-chain exp ----------------
// dA[s]=exp(dt*a[s]); when a[s]=(s+1)*a[0] (A_log=log(arange)), dA[s]=e1^(s+1):
// 1 v_exp + 15 muls (depth-4 tree) instead of 16 v_exp per step. Uniform fallback otherwise.
__device__ __forceinline__ void pow_tree(float e1, float dA[16]){
  float e2 = e1*e1, e4 = e2*e2, e8 = e4*e4;
  dA[0]=e1;      dA[1]=e2;      dA[2]=e2*e1;   dA[3]=e4;
  dA[4]=e4*e1;   dA[5]=e4*e2;   dA[6]=e4*dA[2];dA[7]=e8;
  dA[8]=e8*e1;   dA[9]=e8*e2;   dA[10]=e8*dA[2];dA[11]=e8*e4;
  dA[12]=e8*dA[4];dA[13]=e8*dA[5];dA[14]=e8*dA[6];dA[15]=e8*e8;
}

__global__ __launch_bounds__(256) void k_scanA(
    const float* __restrict__ delta, const unsigned short* __restrict__ u,
    const float* __restrict__ dbc, const float* __restrict__ A_log,
    float* __restrict__ hend, float* __restrict__ aprod)
{
  __shared__ float sBC[CL][32];   // [t][0:16]=B, [16:32]=C
  int tid = threadIdx.x;
  int c = blockIdx.x*256 + tid;
  int k = blockIdx.y;
  float al2[16];
  #pragma unroll
  for (int s = 0; s < 16; s++) al2[s] = -expf(A_log[(size_t)c*16 + s]) * LOG2E;
  bool fast = true;
  #pragma unroll
  for (int s = 1; s < 16; s++)
    fast = fast && (fabsf(al2[s] - (float)(s+1)*al2[0]) <= 1e-4f*fabsf(al2[s]));
  float h[16];
  #pragma unroll
  for (int s = 0; s < 16; s++) h[s] = 0.f;
  float sdt = 0.f;
  for (int idx = tid; idx < CL*32; idx += 256){
    int t = idx >> 5, j = idx & 31;
    sBC[t][j] = dbc[(size_t)(k*CL + t)*128 + 48 + j];
  }
  __syncthreads();
  const float* dp = delta + (size_t)k*CL*DIM + c;
  const unsigned short* up = u + (size_t)k*CL*DIM + c;
  if (fast){
    for (int t = 0; t < CL; t++){
      float dt = dp[t*DIM];
      float uu = bf2f(up[t*DIM]);
      float dtu = dt*uu;
      sdt += dt;
      float dA[16];
      pow_tree(EXP2RAW(dt*al2[0]), dA);
      #pragma unroll
      for (int s = 0; s < 16; s++)
        h[s] = h[s]*dA[s] + dtu*sBC[t][s];
    }
  } else {
    for (int t = 0; t < CL; t++){
      float dt = dp[t*DIM];
      float uu = bf2f(up[t*DIM]);
      float dtu = dt*uu;
      sdt += dt;
      #pragma unroll
      for (int s = 0; s < 16; s++){
        float dA = EXP2RAW(dt*al2[s]);
        h[s] = h[s]*dA + dtu*sBC[t][s];
      }
    }
  }
  size_t base = ((size_t)k*DIM + c)*16;
  #pragma unroll
  for (int s = 0; s < 16; s += 4){
    *(f32x4*)&hend[base+s]  = (f32x4){h[s],h[s+1],h[s+2],h[s+3]};
    // prod over chunk of exp(dt*a) == 2^(al2 * sum dt) exactly
    *(f32x4*)&aprod[base+s] = (f32x4){EXP2RAW(al2[s]*sdt),EXP2RAW(al2[s+1]*sdt),
                                      EXP2RAW(al2[s+2]*sdt),EXP2RAW(al2[s+3]*sdt)};
  }
}

__global__ __launch_bounds__(256) void k_scanB(float* __restrict__ hend, const float* __restrict__ aprod){
  int i = blockIdx.x*256 + threadIdx.x;  // 0..24575 = (c,s) flat
  float H = 0.f;
  for (int k = 0; k < NCH; k++){
    size_t o = (size_t)k*DIM*16 + i;
    float e = hend[o], ap = aprod[o];
    hend[o] = H;          // incoming state for chunk k
    H = e + ap*H;         // exact linear-recurrence composition
  }
}

__global__ __launch_bounds__(256) void k_scanC(
    const float* __restrict__ delta, const unsigned short* __restrict__ u,
    const unsigned short* __restrict__ xz, const float* __restrict__ dbc,
    const float* __restrict__ A_log, const float* __restrict__ D_param,
    const float* __restrict__ hin, unsigned short* __restrict__ y)
{
  __shared__ float sBC[CL][32];
  int tid = threadIdx.x;
  int c = blockIdx.x*256 + tid;
  int k = blockIdx.y;
  float al2[16];
  #pragma unroll
  for (int s = 0; s < 16; s++) al2[s] = -expf(A_log[(size_t)c*16 + s]) * LOG2E;
  bool fast = true;
  #pragma unroll
  for (int s = 1; s < 16; s++)
    fast = fast && (fabsf(al2[s] - (float)(s+1)*al2[0]) <= 1e-4f*fabsf(al2[s]));
  float Dc = D_param[c];
  float h[16];
  size_t base = ((size_t)k*DIM + c)*16;
  #pragma unroll
  for (int s = 0; s < 16; s += 4){
    f32x4 v = *(const f32x4*)&hin[base+s];
    h[s] = v.x; h[s+1] = v.y; h[s+2] = v.z; h[s+3] = v.w;
  }
  for (int idx = tid; idx < CL*32; idx += 256){
    int t = idx >> 5, j = idx & 31;
    sBC[t][j] = dbc[(size_t)(k*CL + t)*128 + 48 + j];
  }
  __syncthreads();
  const float* dp = delta + (size_t)k*CL*DIM + c;
  const unsigned short* up = u + (size_t)k*CL*DIM + c;
  const unsigned short* zp = xz + (size_t)k*CL*3072 + 1536 + c;
  unsigned short* yp = y + (size_t)k*CL*DIM + c;
  if (fast){
    for (int t = 0; t < CL; t++){
      float dt = dp[t*DIM];
      float uu = bf2f(up[t*DIM]);
      float zz = bf2f(zp[t*3072]);
      float dtu = dt*uu;
      float dA[16];
      pow_tree(EXP2RAW(dt*al2[0]), dA);
      float ap[4] = {0.f,0.f,0.f,0.f};   // 4 partial dot chains (shorter latency chain)
      #pragma unroll
      for (int s = 0; s < 16; s++){
        h[s] = h[s]*dA[s] + dtu*sBC[t][s];
        ap[s>>2] += h[s]*sBC[t][16+s];
      }
      float accv = (ap[0]+ap[1]) + (ap[2]+ap[3]);
      float yv = (accv + uu*Dc) * (zz * sigmoidf_(zz));
      yp[t*DIM] = f2bf(yv);
    }
  } else {
    for (int t = 0; t < CL; t++){
      float dt = dp[t*DIM];
      float uu = bf2f(up[t*DIM]);
      float zz = bf2f(zp[t*3072]);
      float dtu = dt*uu;
      float ap[4] = {0.f,0.f,0.f,0.f};
      #pragma unroll
      for (int s = 0; s < 16; s++){
        float dA = EXP2RAW(dt*al2[s]);
        h[s] = h[s]*dA + dtu*sBC[t][s];
        ap[s>>2] += h[s]*sBC[t][16+s];
      }
      float accv = (ap[0]+ap[1]) + (ap[2]+ap[3]);
      float yv = (accv + uu*Dc) * (zz * sigmoidf_(zz));
      yp[t*DIM] = f2bf(yv);
    }
  }
}

// ---------------- GCN aggregation ----------------
__global__ __launch_bounds__(192) void k_aggregate(
    const unsigned short* __restrict__ h, const int* __restrict__ row_ptr,
    const int* __restrict__ csr_src, const float* __restrict__ normS,
    const float* __restrict__ normD, unsigned short* __restrict__ m)
{
  int d = blockIdx.x; int tid = threadIdx.x;
  int e0 = row_ptr[d], e1 = row_ptr[d+1];
  float a0 = 0.f, a1 = 0.f, a2 = 0.f, a3 = 0.f;
  for (int e = e0; e < e1; e++){
    int sI = csr_src[e];
    float ns = normS[sI];
    uint2 v = *((const uint2*)(h + (size_t)sI*DF) + tid);
    a0 += bf2f((unsigned short)(v.x & 0xffff)) * ns;
    a1 += bf2f((unsigned short)(v.x >> 16)) * ns;
    a2 += bf2f((unsigned short)(v.y & 0xffff)) * ns;
    a3 += bf2f((unsigned short)(v.y >> 16)) * ns;
  }
  float nd = normD[d];
  uint2 o;
  o.x = (unsigned int)f2bf(a0*nd) | ((unsigned int)f2bf(a1*nd) << 16);
  o.y = (unsigned int)f2bf(a2*nd) | ((unsigned int)f2bf(a3*nd) << 16);
  *((uint2*)(m + (size_t)d*DF) + tid) = o;
}

// ---------------- finals ----------------
__global__ __launch_bounds__(256) void k_causal(const unsigned short* __restrict__ h,
                                                const float* __restrict__ W_c,
                                                const float* __restrict__ b_c,
                                                float* __restrict__ out){
  int wv = threadIdx.x >> 6, lane = threadIdx.x & 63;
  int r = blockIdx.x*4 + wv;
  float s = 0.f;
  #pragma unroll
  for (int j = 0; j < 12; j++){
    int cidx = lane + 64*j;
    s += bf2f(h[(size_t)r*DF + cidx]) * W_c[cidx];
  }
  s += __shfl_xor(s, 32); s += __shfl_xor(s, 16); s += __shfl_xor(s, 8);
  s += __shfl_xor(s, 4);  s += __shfl_xor(s, 2);  s += __shfl_xor(s, 1);
  if (lane == 0){
    float a = s + b_c[0];
    float cz = sigmoidf_(a);
    out[DF + r] = cz;
    out[DF + NN + r] = (cz > 0.7f) ? 1.f : 0.f;
  }
}

__global__ void k_gfeat(const unsigned short* __restrict__ h, float* __restrict__ out){
  int col = blockIdx.x*256 + threadIdx.x;
  int r0 = blockIdx.y * 512;
  float s = 0.f;
  for (int r = r0; r < r0 + 512; r++) s += bf2f(h[(size_t)r*DF + col]);
  atomicAdd(&out[col], s * (1.f/8192.f));
}

// ---------------- launch ----------------
extern "C" void kernel_launch(void* const* d_in, const int* in_sizes, int n_in,
                              void* d_out, int out_size, void* d_ws, size_t ws_size,
                              hipStream_t stream) {
  const float* node_feats = (const float*)d_in[0];
  const int*   timestamps = (const int*)d_in[1];
  const int*   ei         = (const int*)d_in[2];
  const int*   e_src = ei;
  const int*   e_dst = ei + NE_;
  const float* W_in    = (const float*)d_in[3];
  const float* conv_w  = (const float*)d_in[4];
  const float* conv_b  = (const float*)d_in[5];
  const float* W_xproj = (const float*)d_in[6];
  const float* W_dt    = (const float*)d_in[7];
  const float* b_dt    = (const float*)d_in[8];
  const float* A_log   = (const float*)d_in[9];
  const float* D_param = (const float*)d_in[10];
  const float* W_out   = (const float*)d_in[11];
  const float* Wg      = (const float*)d_in[12];
  const float* bg      = (const float*)d_in[13];
  const float* W_c     = (const float*)d_in[14];
  const float* b_c     = (const float*)d_in[15];
  float* out = (float*)d_out;

  char* ws = (char*)d_ws;
  size_t off = 0;
  auto alloc = [&](size_t bytes) -> char* {
    char* p = ws + off; off += (bytes + 255) & ~(size_t)255; return p;
  };
  unsigned short* WinT   = (unsigned short*)alloc((size_t)3072*768*2);
  unsigned short* WxT    = (unsigned short*)alloc((size_t)128*1536*2);
  unsigned short* WdtT   = (unsigned short*)alloc((size_t)1536*64*2);
  unsigned short* WoutT  = (unsigned short*)alloc((size_t)768*1536*2);
  unsigned short* WgT    = (unsigned short*)alloc((size_t)3*768*768*2);
  unsigned short* seq    = (unsigned short*)alloc((size_t)NN*DF*2);
  unsigned short* xz     = (unsigned short*)alloc((size_t)NN*3072*2);
  unsigned short* ubuf   = (unsigned short*)alloc((size_t)NN*DIM*2);
  float*          dbc    = (float*)alloc((size_t)NN*128*4);
  unsigned short* dt48   = (unsigned short*)alloc((size_t)NN*64*2);
  float*          deltaB = (float*)alloc((size_t)NN*DIM*4);
  unsigned short* ybuf   = (unsigned short*)alloc((size_t)NN*DIM*2);
  unsigned short* hbuf   = (unsigned short*)alloc((size_t)NN*DF*2);
  unsigned short* mbuf   = (unsigned short*)alloc((size_t)NN*DF*2);
  int*   pos    = (int*)alloc((size_t)NN*4);
  int*   degS   = (int*)alloc((size_t)2*NN*4);
  int*   degD   = degS + NN;
  float* normS  = (float*)alloc((size_t)NN*4);
  float* normD  = (float*)alloc((size_t)NN*4);
  int*   rowp   = (int*)alloc((size_t)(NN+1)*4);
  int*   cursor = (int*)alloc((size_t)NN*4);
  int*   csr    = (int*)alloc((size_t)NE_*4);

  // scan chunk summaries (12.58 MB each): hend aliases seq (dead after G1);
  // aprod aliases mbuf (first written by k_aggregate, after the scan)
  float* hend  = (float*)seq;
  float* aprod = (float*)mbuf;

  // zero-init accumulated buffers every call (harness poisons ws/d_out once)
  hipMemsetAsync(degS, 0, (size_t)2*NN*4, stream);
  hipMemsetAsync(pos, 0, (size_t)NN*4, stream);
  hipMemsetAsync(out, 0, (size_t)DF*4, stream);

  // weights: transpose+cast (B operands stored N x K row-major, zero-padded)
  k_transpose_cast<<<dim3(3, 3072), 256, 0, stream>>>(W_in, WinT, 768, 3072, 768);
  k_transpose_cast<<<dim3(6, 128),  256, 0, stream>>>(W_xproj, WxT, 1536, 80, 1536);
  k_transpose_cast<<<dim3(1, 1536), 256, 0, stream>>>(W_dt, WdtT, 48, 1536, 64);
  k_transpose_cast<<<dim3(6, 768),  256, 0, stream>>>(W_out, WoutT, 1536, 768, 1536);
  for (int i = 0; i < 3; i++)
    k_transpose_cast<<<dim3(3, 768), 256, 0, stream>>>(Wg + (size_t)i*768*768, WgT + (size_t)i*768*768, 768, 768, 768);

  // sort + gather (rank 2D-parallel: 32x32 blocks)
  k_rank<<<dim3(NN/256, NN/256), 256, 0, stream>>>(timestamps, pos);
  k_gather<<<NN, 256, 0, stream>>>(node_feats, pos, seq);

  // graph structure
  k_deg_count<<<NE_/256, 256, 0, stream>>>(e_src, e_dst, degS, degD);
  k_norms<<<NN/256, 256, 0, stream>>>(degS, degD, normS, normD);
  k_rowptr<<<1, 1024, 0, stream>>>(degD, rowp, cursor);
  k_csr_fill<<<NE_/256, 256, 0, stream>>>(e_src, e_dst, cursor, csr);

  // G1: xz = seq @ W_in  (8192x3072, K=768)
  k_gemm<0><<<64*24, 256, 0, stream>>>(seq, WinT, 3072, 768, 768, 768,
                                       nullptr, 0, xz, 3072, nullptr, nullptr);
  // conv + silu -> u
  k_conv_silu<<<dim3(6, NN), 256, 0, stream>>>(xz, conv_w, conv_b, ubuf);
  // G2: dbc = u @ W_xproj  (8192x128pad, K=1536); also dt48 bf16 (cols<48)
  k_gemm<1><<<64*1, 256, 0, stream>>>(ubuf, WxT, 128, 1536, 1536, 1536,
                                      dbc, 128, nullptr, 0, nullptr, dt48);
  // G3: delta = softplus(dt48 @ W_dt + b_dt)  (8192x1536, K=64)
  k_gemm<2><<<64*12, 256, 0, stream>>>(dt48, WdtT, 1536, 64, 64, 64,
                                       deltaB, 1536, nullptr, 0, b_dt, nullptr);
  // chunked scan -> y (fused (y + u*D)*silu(z))
  k_scanA<<<dim3(DIM/256, NCH), 256, 0, stream>>>(deltaB, ubuf, dbc, A_log, hend, aprod);
  k_scanB<<<96, 256, 0, stream>>>(hend, aprod);
  k_scanC<<<dim3(DIM/256, NCH), 256, 0, stream>>>(deltaB, ubuf, xz, dbc, A_log, D_param, hend, ybuf);
  // G4: h = y @ W_out  (8192x768, K=1536)
  k_gemm<0><<<64*6, 256, 0, stream>>>(ybuf, WoutT, 768, 1536, 1536, 1536,
                                      nullptr, 0, hbuf, 768, nullptr, nullptr);
  // 3 GCN layers
  for (int i = 0; i < 3; i++){
    k_aggregate<<<NN, 192, 0, stream>>>(hbuf, rowp, csr, normS, normD, mbuf);
    k_gemm<3><<<64*6, 256, 0, stream>>>(mbuf, WgT + (size_t)i*768*768, 768, 768, 768, 768,
                                        nullptr, 0, hbuf, 768, bg + (size_t)i*768, nullptr);
  }
  // finals
  k_causal<<<NN/4, 256, 0, stream>>>(hbuf, W_c, b_c, out);
  k_gfeat<<<dim3(3, 16), 256, 0, stream>>>(hbuf, out);
}

// Round 13
// 773.371 us; speedup vs baseline: 1.0939x; 1.0001x over previous
//
#include <hip/hip_runtime.h>
#include <math.h>

#define NN 8192
#define DF 768
#define NE_ 262144
#define DIM 1536
#define DSN 16
#define NCH 128
#define CL  64   // NN / NCH

typedef short short8 __attribute__((ext_vector_type(8)));
typedef float f32x4 __attribute__((ext_vector_type(4)));

__device__ __forceinline__ float bf2f(unsigned short u){
  unsigned int v = ((unsigned int)u) << 16; float f; __builtin_memcpy(&f, &v, 4); return f;
}
__device__ __forceinline__ unsigned short f2bf(float f){
  unsigned int x; __builtin_memcpy(&x, &f, 4);
  x += 0x7fffu + ((x >> 16) & 1u);
  return (unsigned short)(x >> 16);
}
__device__ __forceinline__ float sigmoidf_(float x){ return 1.f/(1.f+expf(-x)); }
#define EXP2RAW(x) __builtin_amdgcn_exp2f(x)   // single v_exp_f32
#define LOG2E 1.44269504088896f

// ---------------- prep kernels ----------------

__global__ void k_transpose_cast(const float* __restrict__ in, unsigned short* __restrict__ out,
                                 int K, int N, int Kp){
  int k = blockIdx.x*256 + threadIdx.x;
  int n = blockIdx.y;
  if (k >= Kp) return;
  unsigned short v = 0;
  if (k < K && n < N) v = f2bf(in[(size_t)k*N + n]);
  out[(size_t)n*Kp + k] = v;
}

// stable rank, 2D-parallel
__global__ __launch_bounds__(256) void k_rank(const int* __restrict__ ts, int* __restrict__ pos){
  __shared__ int sT[256];
  int i = blockIdx.x*256 + threadIdx.x;
  int my = ts[i];
  int c0 = blockIdx.y*256;
  sT[threadIdx.x] = ts[c0 + threadIdx.x];
  __syncthreads();
  int r = 0;
  #pragma unroll 8
  for (int j = 0; j < 256; j++){
    int t = sT[j]; int jj = c0 + j;
    r += (t < my || (t == my && jj < i)) ? 1 : 0;
  }
  atomicAdd(&pos[i], r);
}

__global__ void k_gather(const float* __restrict__ nf, const int* __restrict__ pos,
                         unsigned short* __restrict__ seq){
  int i = blockIdx.x; int p = pos[i];
  const float* src = nf + (size_t)i*DF;
  unsigned short* dst = seq + (size_t)p*DF;
  for (int j = threadIdx.x; j < DF; j += 256) dst[j] = f2bf(src[j]);
}

__global__ void k_deg_count(const int* __restrict__ esrc, const int* __restrict__ edst,
                            int* __restrict__ degS, int* __restrict__ degD){
  int e = blockIdx.x*256 + threadIdx.x;
  if (e < NE_){ atomicAdd(&degS[esrc[e]], 1); atomicAdd(&degD[edst[e]], 1); }
}

__global__ void k_norms(const int* __restrict__ degS, const int* __restrict__ degD,
                        float* __restrict__ normS, float* __restrict__ normD){
  int i = blockIdx.x*256 + threadIdx.x;
  if (i < NN){
    normS[i] = rsqrtf(fmaxf((float)degS[i], 1.f));
    normD[i] = rsqrtf(fmaxf((float)degD[i], 1.f));
  }
}

__global__ __launch_bounds__(1024) void k_rowptr(const int* __restrict__ degD,
                                                 int* __restrict__ row_ptr, int* __restrict__ cursor){
  __shared__ int sp[1024];
  int tid = threadIdx.x;
  int base = tid*8;
  int loc[8]; int s = 0;
  #pragma unroll
  for (int j = 0; j < 8; j++){ loc[j] = degD[base+j]; s += loc[j]; }
  sp[tid] = s; __syncthreads();
  for (int o = 1; o < 1024; o <<= 1){
    int v = (tid >= o) ? sp[tid-o] : 0; __syncthreads();
    sp[tid] += v; __syncthreads();
  }
  int run = sp[tid] - s;   // exclusive
  #pragma unroll
  for (int j = 0; j < 8; j++){ row_ptr[base+j] = run; cursor[base+j] = run; run += loc[j]; }
  if (tid == 1023) row_ptr[NN] = sp[1023];
}

__global__ void k_csr_fill(const int* __restrict__ esrc, const int* __restrict__ edst,
                           int* __restrict__ cursor, int* __restrict__ csr_src){
  int e = blockIdx.x*256 + threadIdx.x;
  if (e < NE_){
    int d = edst[e];
    int p = atomicAdd(&cursor[d], 1);
    csr_src[p] = esrc[e];
  }
}

// ---------------- bf16 MFMA GEMM (128x128 tile, BK=32, 4 waves) ----------------
// LDS: stride 64 shorts, XOR-swizzled at 8-short granularity: group cg of row r
// stored at cg ^ (r&7). Read (rows +l15, col group l4) and staged write (groups
// 2hf,2hf+1 of row r) are both bank-uniform -> conflict-free.
template<int EPI>
__global__ __launch_bounds__(256) void k_gemm(
    const unsigned short* __restrict__ A, const unsigned short* __restrict__ B,
    int N, int K, int lda, int ldb,
    float* __restrict__ outF, int ldoF,
    unsigned short* __restrict__ outB, int ldoB,
    const float* __restrict__ bias,
    unsigned short* __restrict__ out2)
{
  __shared__ unsigned short sA[128*64];
  __shared__ unsigned short sB[128*64];
  int tid = threadIdx.x;
  int tnc = N >> 7;
  int bm = (blockIdx.x / tnc) << 7;
  int bn = (blockIdx.x % tnc) << 7;
  int wv = tid >> 6, lane = tid & 63;
  int wm = wv >> 1, wn = wv & 1;
  int l15 = lane & 15, l4 = lane >> 4;

  f32x4 acc[4][4];
  #pragma unroll
  for (int i = 0; i < 4; i++)
    #pragma unroll
    for (int j = 0; j < 4; j++)
      acc[i][j] = (f32x4){0.f,0.f,0.f,0.f};

  int r = tid >> 1, hf = tid & 1;
  const unsigned short* gA = A + (size_t)(bm + r)*lda + hf*16;
  const unsigned short* gB = B + (size_t)(bn + r)*ldb + hf*16;

  // swizzled staging destinations (constant over K loop)
  unsigned short* wA0 = &sA[r*64 + (((hf*2    ) ^ (r&7))<<3)];
  unsigned short* wA1 = &sA[r*64 + (((hf*2 + 1) ^ (r&7))<<3)];
  unsigned short* wB0 = &sB[r*64 + (((hf*2    ) ^ (r&7))<<3)];
  unsigned short* wB1 = &sB[r*64 + (((hf*2 + 1) ^ (r&7))<<3)];
  // swizzled fragment-read column groups (row&7 == l15&7 for all i)
  int sw = l15 & 7;

  for (int k0 = 0; k0 < K; k0 += 32){
    short8 va0 = *(const short8*)(gA + k0);
    short8 va1 = *(const short8*)(gA + k0 + 8);
    short8 vb0 = *(const short8*)(gB + k0);
    short8 vb1 = *(const short8*)(gB + k0 + 8);
    __syncthreads();
    *(short8*)wA0 = va0;
    *(short8*)wA1 = va1;
    *(short8*)wB0 = vb0;
    *(short8*)wB1 = vb1;
    __syncthreads();
    short8 af[4], bf_[4];
    #pragma unroll
    for (int i = 0; i < 4; i++){
      af[i]  = *(const short8*)&sA[(wm*64 + i*16 + l15)*64 + ((l4 ^ sw)<<3)];
      bf_[i] = *(const short8*)&sB[(wn*64 + i*16 + l15)*64 + ((l4 ^ sw)<<3)];
    }
    #pragma unroll
    for (int i = 0; i < 4; i++)
      #pragma unroll
      for (int j = 0; j < 4; j++)
        acc[i][j] = __builtin_amdgcn_mfma_f32_16x16x32_bf16(af[i], bf_[j], acc[i][j], 0, 0, 0);
  }

  #pragma unroll
  for (int i = 0; i < 4; i++)
    #pragma unroll
    for (int j = 0; j < 4; j++)
      #pragma unroll
      for (int rr = 0; rr < 4; rr++){
        int row = bm + wm*64 + i*16 + l4*4 + rr;
        int col = bn + wn*64 + j*16 + l15;
        float v = acc[i][j][rr];
        if (EPI == 0){
          outB[(size_t)row*ldoB + col] = f2bf(v);
        } else if (EPI == 1){
          outF[(size_t)row*ldoF + col] = v;
          if (col < 64) out2[(size_t)row*64 + col] = (col < 48) ? f2bf(v) : (unsigned short)0;
        } else if (EPI == 2){
          v += bias[col];
          float sp = (v > 20.f) ? v : log1pf(expf(v));
          outF[(size_t)row*ldoF + col] = sp;
        } else {
          v += bias[col];
          float g = 0.5f*v*(1.f + erff(v*0.70710678118f));
          outB[(size_t)row*ldoB + col] = f2bf(g);
        }
      }
}

// ---------------- causal conv + silu ----------------
__global__ void k_conv_silu(const unsigned short* __restrict__ xz, const float* __restrict__ conv_w,
                            const float* __restrict__ conv_b, unsigned short* __restrict__ u){
  int c = blockIdx.x*256 + threadIdx.x;  // 0..1535
  int t = blockIdx.y;
  float acc = conv_b[c];
  #pragma unroll
  for (int k = 0; k < 4; k++){
    int tt = t - 3 + k;
    if (tt >= 0) acc += bf2f(xz[(size_t)tt*3072 + c]) * conv_w[c*4 + k];
  }
  u[(size_t)t*DIM + c] = f2bf(acc * sigmoidf_(acc));
}

// ---------------- selective scan: chunked parallel + power-chain exp ----------------
__device__ __forceinline__ void pow_tree(float e1, float dA[16]){
  float e2 = e1*e1, e4 = e2*e2, e8 = e4*e4;
  dA[0]=e1;      dA[1]=e2;      dA[2]=e2*e1;   dA[3]=e4;
  dA[4]=e4*e1;   dA[5]=e4*e2;   dA[6]=e4*dA[2];dA[7]=e8;
  dA[8]=e8*e1;   dA[9]=e8*e2;   dA[10]=e8*dA[2];dA[11]=e8*e4;
  dA[12]=e8*dA[4];dA[13]=e8*dA[5];dA[14]=e8*dA[6];dA[15]=e8*e8;
}

__global__ __launch_bounds__(256) void k_scanA(
    const float* __restrict__ delta, const unsigned short* __restrict__ u,
    const float* __restrict__ dbc, const float* __restrict__ A_log,
    float* __restrict__ hend, float* __restrict__ aprod)
{
  __shared__ float sBC[CL][32];   // [t][0:16]=B, [16:32]=C
  int tid = threadIdx.x;
  int c = blockIdx.x*256 + tid;
  int k = blockIdx.y;
  float al2[16];
  #pragma unroll
  for (int s = 0; s < 16; s++) al2[s] = -expf(A_log[(size_t)c*16 + s]) * LOG2E;
  bool fast = true;
  #pragma unroll
  for (int s = 1; s < 16; s++)
    fast = fast && (fabsf(al2[s] - (float)(s+1)*al2[0]) <= 1e-4f*fabsf(al2[s]));
  float h[16];
  #pragma unroll
  for (int s = 0; s < 16; s++) h[s] = 0.f;
  float sdt = 0.f;
  for (int idx = tid; idx < CL*32; idx += 256){
    int t = idx >> 5, j = idx & 31;
    sBC[t][j] = dbc[(size_t)(k*CL + t)*128 + 48 + j];
  }
  __syncthreads();
  const float* dp = delta + (size_t)k*CL*DIM + c;
  const unsigned short* up = u + (size_t)k*CL*DIM + c;
  if (fast){
    for (int t = 0; t < CL; t++){
      float dt = dp[t*DIM];
      float uu = bf2f(up[t*DIM]);
      float dtu = dt*uu;
      sdt += dt;
      float dA[16];
      pow_tree(EXP2RAW(dt*al2[0]), dA);
      #pragma unroll
      for (int s = 0; s < 16; s++)
        h[s] = h[s]*dA[s] + dtu*sBC[t][s];
    }
  } else {
    for (int t = 0; t < CL; t++){
      float dt = dp[t*DIM];
      float uu = bf2f(up[t*DIM]);
      float dtu = dt*uu;
      sdt += dt;
      #pragma unroll
      for (int s = 0; s < 16; s++){
        float dA = EXP2RAW(dt*al2[s]);
        h[s] = h[s]*dA + dtu*sBC[t][s];
      }
    }
  }
  size_t base = ((size_t)k*DIM + c)*16;
  #pragma unroll
  for (int s = 0; s < 16; s += 4){
    *(f32x4*)&hend[base+s]  = (f32x4){h[s],h[s+1],h[s+2],h[s+3]};
    *(f32x4*)&aprod[base+s] = (f32x4){EXP2RAW(al2[s]*sdt),EXP2RAW(al2[s+1]*sdt),
                                      EXP2RAW(al2[s+2]*sdt),EXP2RAW(al2[s+3]*sdt)};
  }
}

__global__ __launch_bounds__(256) void k_scanB(float* __restrict__ hend, const float* __restrict__ aprod){
  int i = blockIdx.x*256 + threadIdx.x;  // 0..24575 = (c,s) flat
  float H = 0.f;
  for (int k = 0; k < NCH; k++){
    size_t o = (size_t)k*DIM*16 + i;
    float e = hend[o], ap = aprod[o];
    hend[o] = H;          // incoming state for chunk k
    H = e + ap*H;         // exact linear-recurrence composition
  }
}

__global__ __launch_bounds__(256) void k_scanC(
    const float* __restrict__ delta, const unsigned short* __restrict__ u,
    const unsigned short* __restrict__ xz, const float* __restrict__ dbc,
    const float* __restrict__ A_log, const float* __restrict__ D_param,
    const float* __restrict__ hin, unsigned short* __restrict__ y)
{
  __shared__ float sBC[CL][32];
  int tid = threadIdx.x;
  int c = blockIdx.x*256 + tid;
  int k = blockIdx.y;
  float al2[16];
  #pragma unroll
  for (int s = 0; s < 16; s++) al2[s] = -expf(A_log[(size_t)c*16 + s]) * LOG2E;
  bool fast = true;
  #pragma unroll
  for (int s = 1; s < 16; s++)
    fast = fast && (fabsf(al2[s] - (float)(s+1)*al2[0]) <= 1e-4f*fabsf(al2[s]));
  float Dc = D_param[c];
  float h[16];
  size_t base = ((size_t)k*DIM + c)*16;
  #pragma unroll
  for (int s = 0; s < 16; s += 4){
    f32x4 v = *(const f32x4*)&hin[base+s];
    h[s] = v.x; h[s+1] = v.y; h[s+2] = v.z; h[s+3] = v.w;
  }
  for (int idx = tid; idx < CL*32; idx += 256){
    int t = idx >> 5, j = idx & 31;
    sBC[t][j] = dbc[(size_t)(k*CL + t)*128 + 48 + j];
  }
  __syncthreads();
  const float* dp = delta + (size_t)k*CL*DIM + c;
  const unsigned short* up = u + (size_t)k*CL*DIM + c;
  const unsigned short* zp = xz + (size_t)k*CL*3072 + 1536 + c;
  unsigned short* yp = y + (size_t)k*CL*DIM + c;
  if (fast){
    for (int t = 0; t < CL; t++){
      float dt = dp[t*DIM];
      float uu = bf2f(up[t*DIM]);
      float zz = bf2f(zp[t*3072]);
      float dtu = dt*uu;
      float dA[16];
      pow_tree(EXP2RAW(dt*al2[0]), dA);
      float ap[4] = {0.f,0.f,0.f,0.f};
      #pragma unroll
      for (int s = 0; s < 16; s++){
        h[s] = h[s]*dA[s] + dtu*sBC[t][s];
        ap[s>>2] += h[s]*sBC[t][16+s];
      }
      float accv = (ap[0]+ap[1]) + (ap[2]+ap[3]);
      float yv = (accv + uu*Dc) * (zz * sigmoidf_(zz));
      yp[t*DIM] = f2bf(yv);
    }
  } else {
    for (int t = 0; t < CL; t++){
      float dt = dp[t*DIM];
      float uu = bf2f(up[t*DIM]);
      float zz = bf2f(zp[t*3072]);
      float dtu = dt*uu;
      float ap[4] = {0.f,0.f,0.f,0.f};
      #pragma unroll
      for (int s = 0; s < 16; s++){
        float dA = EXP2RAW(dt*al2[s]);
        h[s] = h[s]*dA + dtu*sBC[t][s];
        ap[s>>2] += h[s]*sBC[t][16+s];
      }
      float accv = (ap[0]+ap[1]) + (ap[2]+ap[3]);
      float yv = (accv + uu*Dc) * (zz * sigmoidf_(zz));
      yp[t*DIM] = f2bf(yv);
    }
  }
}

// ---------------- GCN aggregation ----------------
__global__ __launch_bounds__(192) void k_aggregate(
    const unsigned short* __restrict__ h, const int* __restrict__ row_ptr,
    const int* __restrict__ csr_src, const float* __restrict__ normS,
    const float* __restrict__ normD, unsigned short* __restrict__ m)
{
  int d = blockIdx.x; int tid = threadIdx.x;
  int e0 = row_ptr[d], e1 = row_ptr[d+1];
  float a0 = 0.f, a1 = 0.f, a2 = 0.f, a3 = 0.f;
  for (int e = e0; e < e1; e++){
    int sI = csr_src[e];
    float ns = normS[sI];
    uint2 v = *((const uint2*)(h + (size_t)sI*DF) + tid);
    a0 += bf2f((unsigned short)(v.x & 0xffff)) * ns;
    a1 += bf2f((unsigned short)(v.x >> 16)) * ns;
    a2 += bf2f((unsigned short)(v.y & 0xffff)) * ns;
    a3 += bf2f((unsigned short)(v.y >> 16)) * ns;
  }
  float nd = normD[d];
  uint2 o;
  o.x = (unsigned int)f2bf(a0*nd) | ((unsigned int)f2bf(a1*nd) << 16);
  o.y = (unsigned int)f2bf(a2*nd) | ((unsigned int)f2bf(a3*nd) << 16);
  *((uint2*)(m + (size_t)d*DF) + tid) = o;
}

// ---------------- finals ----------------
__global__ __launch_bounds__(256) void k_causal(const unsigned short* __restrict__ h,
                                                const float* __restrict__ W_c,
                                                const float* __restrict__ b_c,
                                                float* __restrict__ out){
  int wv = threadIdx.x >> 6, lane = threadIdx.x & 63;
  int r = blockIdx.x*4 + wv;
  float s = 0.f;
  #pragma unroll
  for (int j = 0; j < 12; j++){
    int cidx = lane + 64*j;
    s += bf2f(h[(size_t)r*DF + cidx]) * W_c[cidx];
  }
  s += __shfl_xor(s, 32); s += __shfl_xor(s, 16); s += __shfl_xor(s, 8);
  s += __shfl_xor(s, 4);  s += __shfl_xor(s, 2);  s += __shfl_xor(s, 1);
  if (lane == 0){
    float a = s + b_c[0];
    float cz = sigmoidf_(a);
    out[DF + r] = cz;
    out[DF + NN + r] = (cz > 0.7f) ? 1.f : 0.f;
  }
}

__global__ void k_gfeat(const unsigned short* __restrict__ h, float* __restrict__ out){
  int col = blockIdx.x*256 + threadIdx.x;
  int r0 = blockIdx.y * 512;
  float s = 0.f;
  for (int r = r0; r < r0 + 512; r++) s += bf2f(h[(size_t)r*DF + col]);
  atomicAdd(&out[col], s * (1.f/8192.f));
}

// ---------------- launch ----------------
extern "C" void kernel_launch(void* const* d_in, const int* in_sizes, int n_in,
                              void* d_out, int out_size, void* d_ws, size_t ws_size,
                              hipStream_t stream) {
  const float* node_feats = (const float*)d_in[0];
  const int*   timestamps = (const int*)d_in[1];
  const int*   ei         = (const int*)d_in[2];
  const int*   e_src = ei;
  const int*   e_dst = ei + NE_;
  const float* W_in    = (const float*)d_in[3];
  const float* conv_w  = (const float*)d_in[4];
  const float* conv_b  = (const float*)d_in[5];
  const float* W_xproj = (const float*)d_in[6];
  const float* W_dt    = (const float*)d_in[7];
  const float* b_dt    = (const float*)d_in[8];
  const float* A_log   = (const float*)d_in[9];
  const float* D_param = (const float*)d_in[10];
  const float* W_out   = (const float*)d_in[11];
  const float* Wg      = (const float*)d_in[12];
  const float* bg      = (const float*)d_in[13];
  const float* W_c     = (const float*)d_in[14];
  const float* b_c     = (const float*)d_in[15];
  float* out = (float*)d_out;

  char* ws = (char*)d_ws;
  size_t off = 0;
  auto alloc = [&](size_t bytes) -> char* {
    char* p = ws + off; off += (bytes + 255) & ~(size_t)255; return p;
  };
  unsigned short* WinT   = (unsigned short*)alloc((size_t)3072*768*2);
  unsigned short* WxT    = (unsigned short*)alloc((size_t)128*1536*2);
  unsigned short* WdtT   = (unsigned short*)alloc((size_t)1536*64*2);
  unsigned short* WoutT  = (unsigned short*)alloc((size_t)768*1536*2);
  unsigned short* WgT    = (unsigned short*)alloc((size_t)3*768*768*2);
  unsigned short* seq    = (unsigned short*)alloc((size_t)NN*DF*2);
  unsigned short* xz     = (unsigned short*)alloc((size_t)NN*3072*2);
  unsigned short* ubuf   = (unsigned short*)alloc((size_t)NN*DIM*2);
  float*          dbc    = (float*)alloc((size_t)NN*128*4);
  unsigned short* dt48   = (unsigned short*)alloc((size_t)NN*64*2);
  float*          deltaB = (float*)alloc((size_t)NN*DIM*4);
  unsigned short* ybuf   = (unsigned short*)alloc((size_t)NN*DIM*2);
  unsigned short* hbuf   = (unsigned short*)alloc((size_t)NN*DF*2);
  unsigned short* mbuf   = (unsigned short*)alloc((size_t)NN*DF*2);
  int*   pos    = (int*)alloc((size_t)NN*4);
  int*   degS   = (int*)alloc((size_t)2*NN*4);
  int*   degD   = degS + NN;
  float* normS  = (float*)alloc((size_t)NN*4);
  float* normD  = (float*)alloc((size_t)NN*4);
  int*   rowp   = (int*)alloc((size_t)(NN+1)*4);
  int*   cursor = (int*)alloc((size_t)NN*4);
  int*   csr    = (int*)alloc((size_t)NE_*4);

  // scan chunk summaries (12.58 MB each): hend aliases seq (dead after G1);
  // aprod aliases mbuf (first written by k_aggregate, after the scan)
  float* hend  = (float*)seq;
  float* aprod = (float*)mbuf;

  // zero-init accumulated buffers every call (harness poisons ws/d_out once)
  hipMemsetAsync(degS, 0, (size_t)2*NN*4, stream);
  hipMemsetAsync(pos, 0, (size_t)NN*4, stream);
  hipMemsetAsync(out, 0, (size_t)DF*4, stream);

  // weights: transpose+cast (B operands stored N x K row-major, zero-padded)
  k_transpose_cast<<<dim3(3, 3072), 256, 0, stream>>>(W_in, WinT, 768, 3072, 768);
  k_transpose_cast<<<dim3(6, 128),  256, 0, stream>>>(W_xproj, WxT, 1536, 80, 1536);
  k_transpose_cast<<<dim3(1, 1536), 256, 0, stream>>>(W_dt, WdtT, 48, 1536, 64);
  k_transpose_cast<<<dim3(6, 768),  256, 0, stream>>>(W_out, WoutT, 1536, 768, 1536);
  for (int i = 0; i < 3; i++)
    k_transpose_cast<<<dim3(3, 768), 256, 0, stream>>>(Wg + (size_t)i*768*768, WgT + (size_t)i*768*768, 768, 768, 768);

  // sort + gather (rank 2D-parallel: 32x32 blocks)
  k_rank<<<dim3(NN/256, NN/256), 256, 0, stream>>>(timestamps, pos);
  k_gather<<<NN, 256, 0, stream>>>(node_feats, pos, seq);

  // graph structure
  k_deg_count<<<NE_/256, 256, 0, stream>>>(e_src, e_dst, degS, degD);
  k_norms<<<NN/256, 256, 0, stream>>>(degS, degD, normS, normD);
  k_rowptr<<<1, 1024, 0, stream>>>(degD, rowp, cursor);
  k_csr_fill<<<NE_/256, 256, 0, stream>>>(e_src, e_dst, cursor, csr);

  // G1: xz = seq @ W_in  (8192x3072, K=768)
  k_gemm<0><<<64*24, 256, 0, stream>>>(seq, WinT, 3072, 768, 768, 768,
                                       nullptr, 0, xz, 3072, nullptr, nullptr);
  // conv + silu -> u
  k_conv_silu<<<dim3(6, NN), 256, 0, stream>>>(xz, conv_w, conv_b, ubuf);
  // G2: dbc = u @ W_xproj  (8192x128pad, K=1536); also dt48 bf16 (cols<48)
  k_gemm<1><<<64*1, 256, 0, stream>>>(ubuf, WxT, 128, 1536, 1536, 1536,
                                      dbc, 128, nullptr, 0, nullptr, dt48);
  // G3: delta = softplus(dt48 @ W_dt + b_dt)  (8192x1536, K=64)
  k_gemm<2><<<64*12, 256, 0, stream>>>(dt48, WdtT, 1536, 64, 64, 64,
                                       deltaB, 1536, nullptr, 0, b_dt, nullptr);
  // chunked scan -> y (fused (y + u*D)*silu(z))
  k_scanA<<<dim3(DIM/256, NCH), 256, 0, stream>>>(deltaB, ubuf, dbc, A_log, hend, aprod);
  k_scanB<<<96, 256, 0, stream>>>(hend, aprod);
  k_scanC<<<dim3(DIM/256, NCH), 256, 0, stream>>>(deltaB, ubuf, xz, dbc, A_log, D_param, hend, ybuf);
  // G4: h = y @ W_out  (8192x768, K=1536)
  k_gemm<0><<<64*6, 256, 0, stream>>>(ybuf, WoutT, 768, 1536, 1536, 1536,
                                      nullptr, 0, hbuf, 768, nullptr, nullptr);
  // 3 GCN layers
  for (int i = 0; i < 3; i++){
    k_aggregate<<<NN, 192, 0, stream>>>(hbuf, rowp, csr, normS, normD, mbuf);
    k_gemm<3><<<64*6, 256, 0, stream>>>(mbuf, WgT + (size_t)i*768*768, 768, 768, 768, 768,
                                        nullptr, 0, hbuf, 768, bg + (size_t)i*768, nullptr);
  }
  // finals
  k_causal<<<NN/4, 256, 0, stream>>>(hbuf, W_c, b_c, out);
  k_gfeat<<<dim3(3, 16), 256, 0, stream>>>(hbuf, out);
}

// Round 14
// 766.543 us; speedup vs baseline: 1.1036x; 1.0089x over previous
//
#include <hip/hip_runtime.h>
#include <math.h>

#define NN 8192
#define DF 768
#define NE_ 262144
#define DIM 1536
#define DSN 16
#define NCH 128
#define CL  64   // NN / NCH

typedef short short8 __attribute__((ext_vector_type(8)));
typedef float f32x4 __attribute__((ext_vector_type(4)));

__device__ __forceinline__ float bf2f(unsigned short u){
  unsigned int v = ((unsigned int)u) << 16; float f; __builtin_memcpy(&f, &v, 4); return f;
}
__device__ __forceinline__ unsigned short f2bf(float f){
  unsigned int x; __builtin_memcpy(&x, &f, 4);
  x += 0x7fffu + ((x >> 16) & 1u);
  return (unsigned short)(x >> 16);
}
__device__ __forceinline__ float sigmoidf_(float x){ return 1.f/(1.f+expf(-x)); }
#define EXP2RAW(x) __builtin_amdgcn_exp2f(x)   // single v_exp_f32
#define LOG2E 1.44269504088896f

// async global->LDS, 16B per lane; LDS dest is wave-uniform base + lane*16
__device__ __forceinline__ void gl_lds16(const unsigned short* g, unsigned short* l){
  __builtin_amdgcn_global_load_lds(
      (const __attribute__((address_space(1))) unsigned int*)g,
      (__attribute__((address_space(3))) unsigned int*)l,
      16, 0, 0);
}

// ---------------- prep kernels ----------------

__global__ void k_transpose_cast(const float* __restrict__ in, unsigned short* __restrict__ out,
                                 int K, int N, int Kp){
  int k = blockIdx.x*256 + threadIdx.x;
  int n = blockIdx.y;
  if (k >= Kp) return;
  unsigned short v = 0;
  if (k < K && n < N) v = f2bf(in[(size_t)k*N + n]);
  out[(size_t)n*Kp + k] = v;
}

// stable rank, 2D-parallel
__global__ __launch_bounds__(256) void k_rank(const int* __restrict__ ts, int* __restrict__ pos){
  __shared__ int sT[256];
  int i = blockIdx.x*256 + threadIdx.x;
  int my = ts[i];
  int c0 = blockIdx.y*256;
  sT[threadIdx.x] = ts[c0 + threadIdx.x];
  __syncthreads();
  int r = 0;
  #pragma unroll 8
  for (int j = 0; j < 256; j++){
    int t = sT[j]; int jj = c0 + j;
    r += (t < my || (t == my && jj < i)) ? 1 : 0;
  }
  atomicAdd(&pos[i], r);
}

__global__ void k_gather(const float* __restrict__ nf, const int* __restrict__ pos,
                         unsigned short* __restrict__ seq){
  int i = blockIdx.x; int p = pos[i];
  const float* src = nf + (size_t)i*DF;
  unsigned short* dst = seq + (size_t)p*DF;
  for (int j = threadIdx.x; j < DF; j += 256) dst[j] = f2bf(src[j]);
}

__global__ void k_deg_count(const int* __restrict__ esrc, const int* __restrict__ edst,
                            int* __restrict__ degS, int* __restrict__ degD){
  int e = blockIdx.x*256 + threadIdx.x;
  if (e < NE_){ atomicAdd(&degS[esrc[e]], 1); atomicAdd(&degD[edst[e]], 1); }
}

__global__ void k_norms(const int* __restrict__ degS, const int* __restrict__ degD,
                        float* __restrict__ normS, float* __restrict__ normD){
  int i = blockIdx.x*256 + threadIdx.x;
  if (i < NN){
    normS[i] = rsqrtf(fmaxf((float)degS[i], 1.f));
    normD[i] = rsqrtf(fmaxf((float)degD[i], 1.f));
  }
}

__global__ __launch_bounds__(1024) void k_rowptr(const int* __restrict__ degD,
                                                 int* __restrict__ row_ptr, int* __restrict__ cursor){
  __shared__ int sp[1024];
  int tid = threadIdx.x;
  int base = tid*8;
  int loc[8]; int s = 0;
  #pragma unroll
  for (int j = 0; j < 8; j++){ loc[j] = degD[base+j]; s += loc[j]; }
  sp[tid] = s; __syncthreads();
  for (int o = 1; o < 1024; o <<= 1){
    int v = (tid >= o) ? sp[tid-o] : 0; __syncthreads();
    sp[tid] += v; __syncthreads();
  }
  int run = sp[tid] - s;   // exclusive
  #pragma unroll
  for (int j = 0; j < 8; j++){ row_ptr[base+j] = run; cursor[base+j] = run; run += loc[j]; }
  if (tid == 1023) row_ptr[NN] = sp[1023];
}

__global__ void k_csr_fill(const int* __restrict__ esrc, const int* __restrict__ edst,
                           int* __restrict__ cursor, int* __restrict__ csr_src){
  int e = blockIdx.x*256 + threadIdx.x;
  if (e < NE_){
    int d = edst[e];
    int p = atomicAdd(&cursor[d], 1);
    csr_src[p] = esrc[e];
  }
}

// ---------------- bf16 MFMA GEMM (128x128 tile, BK=32, 4 waves) ----------------
// Staging via global_load_lds width=16 (m97 structure): linear [128][32] LDS tiles.
// Wave wv issues chunks ci=wv*2+q; lane l covers row ci*16+(l>>2), col (l&3)*8.
template<int EPI>
__global__ __launch_bounds__(256) void k_gemm(
    const unsigned short* __restrict__ A, const unsigned short* __restrict__ B,
    int N, int K, int lda, int ldb,
    float* __restrict__ outF, int ldoF,
    unsigned short* __restrict__ outB, int ldoB,
    const float* __restrict__ bias,
    unsigned short* __restrict__ out2)
{
  __shared__ unsigned short sA[128*32];
  __shared__ unsigned short sB[128*32];
  int tid = threadIdx.x;
  int tnc = N >> 7;
  int bm = (blockIdx.x / tnc) << 7;
  int bn = (blockIdx.x % tnc) << 7;
  int wv = tid >> 6, lane = tid & 63;
  int wm = wv >> 1, wn = wv & 1;
  int l15 = lane & 15, l4 = lane >> 4;

  f32x4 acc[4][4];
  #pragma unroll
  for (int i = 0; i < 4; i++)
    #pragma unroll
    for (int j = 0; j < 4; j++)
      acc[i][j] = (f32x4){0.f,0.f,0.f,0.f};

  // staging geometry
  int r0 = (wv*2)*16 + (lane >> 2);
  int r1 = r0 + 16;
  int cc = (lane & 3)*8;
  const unsigned short* gA0 = A + (size_t)(bm + r0)*lda + cc;
  const unsigned short* gA1 = A + (size_t)(bm + r1)*lda + cc;
  const unsigned short* gB0 = B + (size_t)(bn + r0)*ldb + cc;
  const unsigned short* gB1 = B + (size_t)(bn + r1)*ldb + cc;
  unsigned short* lA0 = &sA[(size_t)(wv*2)*512];
  unsigned short* lA1 = lA0 + 512;
  unsigned short* lB0 = &sB[(size_t)(wv*2)*512];
  unsigned short* lB1 = lB0 + 512;

  for (int k0 = 0; k0 < K; k0 += 32){
    __syncthreads();     // all waves done reading previous tile
    gl_lds16(gA0 + k0, lA0);
    gl_lds16(gA1 + k0, lA1);
    gl_lds16(gB0 + k0, lB0);
    gl_lds16(gB1 + k0, lB1);
    __syncthreads();     // compiler drains vmcnt(0) before barrier -> tile ready
    short8 af[4], bf_[4];
    #pragma unroll
    for (int i = 0; i < 4; i++){
      af[i]  = *(const short8*)&sA[(wm*64 + i*16 + l15)*32 + l4*8];
      bf_[i] = *(const short8*)&sB[(wn*64 + i*16 + l15)*32 + l4*8];
    }
    #pragma unroll
    for (int i = 0; i < 4; i++)
      #pragma unroll
      for (int j = 0; j < 4; j++)
        acc[i][j] = __builtin_amdgcn_mfma_f32_16x16x32_bf16(af[i], bf_[j], acc[i][j], 0, 0, 0);
  }

  #pragma unroll
  for (int i = 0; i < 4; i++)
    #pragma unroll
    for (int j = 0; j < 4; j++)
      #pragma unroll
      for (int rr = 0; rr < 4; rr++){
        int row = bm + wm*64 + i*16 + l4*4 + rr;
        int col = bn + wn*64 + j*16 + l15;
        float v = acc[i][j][rr];
        if (EPI == 0){
          outB[(size_t)row*ldoB + col] = f2bf(v);
        } else if (EPI == 1){
          outF[(size_t)row*ldoF + col] = v;
          if (col < 64) out2[(size_t)row*64 + col] = (col < 48) ? f2bf(v) : (unsigned short)0;
        } else if (EPI == 2){
          v += bias[col];
          float sp = (v > 20.f) ? v : log1pf(expf(v));
          outF[(size_t)row*ldoF + col] = sp;
        } else {
          v += bias[col];
          float g = 0.5f*v*(1.f + erff(v*0.70710678118f));
          outB[(size_t)row*ldoB + col] = f2bf(g);
        }
      }
}

// ---------------- causal conv + silu ----------------
__global__ void k_conv_silu(const unsigned short* __restrict__ xz, const float* __restrict__ conv_w,
                            const float* __restrict__ conv_b, unsigned short* __restrict__ u){
  int c = blockIdx.x*256 + threadIdx.x;  // 0..1535
  int t = blockIdx.y;
  float acc = conv_b[c];
  #pragma unroll
  for (int k = 0; k < 4; k++){
    int tt = t - 3 + k;
    if (tt >= 0) acc += bf2f(xz[(size_t)tt*3072 + c]) * conv_w[c*4 + k];
  }
  u[(size_t)t*DIM + c] = f2bf(acc * sigmoidf_(acc));
}

// ---------------- selective scan: chunked parallel + power-chain exp ----------------
__device__ __forceinline__ void pow_tree(float e1, float dA[16]){
  float e2 = e1*e1, e4 = e2*e2, e8 = e4*e4;
  dA[0]=e1;      dA[1]=e2;      dA[2]=e2*e1;   dA[3]=e4;
  dA[4]=e4*e1;   dA[5]=e4*e2;   dA[6]=e4*dA[2];dA[7]=e8;
  dA[8]=e8*e1;   dA[9]=e8*e2;   dA[10]=e8*dA[2];dA[11]=e8*e4;
  dA[12]=e8*dA[4];dA[13]=e8*dA[5];dA[14]=e8*dA[6];dA[15]=e8*e8;
}

__global__ __launch_bounds__(256) void k_scanA(
    const float* __restrict__ delta, const unsigned short* __restrict__ u,
    const float* __restrict__ dbc, const float* __restrict__ A_log,
    float* __restrict__ hend, float* __restrict__ aprod)
{
  __shared__ float sBC[CL][32];   // [t][0:16]=B, [16:32]=C
  int tid = threadIdx.x;
  int c = blockIdx.x*256 + tid;
  int k = blockIdx.y;
  float al2[16];
  #pragma unroll
  for (int s = 0; s < 16; s++) al2[s] = -expf(A_log[(size_t)c*16 + s]) * LOG2E;
  bool fast = true;
  #pragma unroll
  for (int s = 1; s < 16; s++)
    fast = fast && (fabsf(al2[s] - (float)(s+1)*al2[0]) <= 1e-4f*fabsf(al2[s]));
  float h[16];
  #pragma unroll
  for (int s = 0; s < 16; s++) h[s] = 0.f;
  float sdt = 0.f;
  for (int idx = tid; idx < CL*32; idx += 256){
    int t = idx >> 5, j = idx & 31;
    sBC[t][j] = dbc[(size_t)(k*CL + t)*128 + 48 + j];
  }
  __syncthreads();
  const float* dp = delta + (size_t)k*CL*DIM + c;
  const unsigned short* up = u + (size_t)k*CL*DIM + c;
  if (fast){
    for (int t = 0; t < CL; t++){
      float dt = dp[t*DIM];
      float uu = bf2f(up[t*DIM]);
      float dtu = dt*uu;
      sdt += dt;
      float dA[16];
      pow_tree(EXP2RAW(dt*al2[0]), dA);
      #pragma unroll
      for (int s = 0; s < 16; s++)
        h[s] = h[s]*dA[s] + dtu*sBC[t][s];
    }
  } else {
    for (int t = 0; t < CL; t++){
      float dt = dp[t*DIM];
      float uu = bf2f(up[t*DIM]);
      float dtu = dt*uu;
      sdt += dt;
      #pragma unroll
      for (int s = 0; s < 16; s++){
        float dA = EXP2RAW(dt*al2[s]);
        h[s] = h[s]*dA + dtu*sBC[t][s];
      }
    }
  }
  size_t base = ((size_t)k*DIM + c)*16;
  #pragma unroll
  for (int s = 0; s < 16; s += 4){
    *(f32x4*)&hend[base+s]  = (f32x4){h[s],h[s+1],h[s+2],h[s+3]};
    *(f32x4*)&aprod[base+s] = (f32x4){EXP2RAW(al2[s]*sdt),EXP2RAW(al2[s+1]*sdt),
                                      EXP2RAW(al2[s+2]*sdt),EXP2RAW(al2[s+3]*sdt)};
  }
}

__global__ __launch_bounds__(256) void k_scanB(float* __restrict__ hend, const float* __restrict__ aprod){
  int i = blockIdx.x*256 + threadIdx.x;  // 0..24575 = (c,s) flat
  float H = 0.f;
  for (int k = 0; k < NCH; k++){
    size_t o = (size_t)k*DIM*16 + i;
    float e = hend[o], ap = aprod[o];
    hend[o] = H;          // incoming state for chunk k
    H = e + ap*H;         // exact linear-recurrence composition
  }
}

__global__ __launch_bounds__(256) void k_scanC(
    const float* __restrict__ delta, const unsigned short* __restrict__ u,
    const unsigned short* __restrict__ xz, const float* __restrict__ dbc,
    const float* __restrict__ A_log, const float* __restrict__ D_param,
    const float* __restrict__ hin, unsigned short* __restrict__ y)
{
  __shared__ float sBC[CL][32];
  int tid = threadIdx.x;
  int c = blockIdx.x*256 + tid;
  int k = blockIdx.y;
  float al2[16];
  #pragma unroll
  for (int s = 0; s < 16; s++) al2[s] = -expf(A_log[(size_t)c*16 + s]) * LOG2E;
  bool fast = true;
  #pragma unroll
  for (int s = 1; s < 16; s++)
    fast = fast && (fabsf(al2[s] - (float)(s+1)*al2[0]) <= 1e-4f*fabsf(al2[s]));
  float Dc = D_param[c];
  float h[16];
  size_t base = ((size_t)k*DIM + c)*16;
  #pragma unroll
  for (int s = 0; s < 16; s += 4){
    f32x4 v = *(const f32x4*)&hin[base+s];
    h[s] = v.x; h[s+1] = v.y; h[s+2] = v.z; h[s+3] = v.w;
  }
  for (int idx = tid; idx < CL*32; idx += 256){
    int t = idx >> 5, j = idx & 31;
    sBC[t][j] = dbc[(size_t)(k*CL + t)*128 + 48 + j];
  }
  __syncthreads();
  const float* dp = delta + (size_t)k*CL*DIM + c;
  const unsigned short* up = u + (size_t)k*CL*DIM + c;
  const unsigned short* zp = xz + (size_t)k*CL*3072 + 1536 + c;
  unsigned short* yp = y + (size_t)k*CL*DIM + c;
  if (fast){
    for (int t = 0; t < CL; t++){
      float dt = dp[t*DIM];
      float uu = bf2f(up[t*DIM]);
      float zz = bf2f(zp[t*3072]);
      float dtu = dt*uu;
      float dA[16];
      pow_tree(EXP2RAW(dt*al2[0]), dA);
      float ap[4] = {0.f,0.f,0.f,0.f};
      #pragma unroll
      for (int s = 0; s < 16; s++){
        h[s] = h[s]*dA[s] + dtu*sBC[t][s];
        ap[s>>2] += h[s]*sBC[t][16+s];
      }
      float accv = (ap[0]+ap[1]) + (ap[2]+ap[3]);
      float yv = (accv + uu*Dc) * (zz * sigmoidf_(zz));
      yp[t*DIM] = f2bf(yv);
    }
  } else {
    for (int t = 0; t < CL; t++){
      float dt = dp[t*DIM];
      float uu = bf2f(up[t*DIM]);
      float zz = bf2f(zp[t*3072]);
      float dtu = dt*uu;
      float ap[4] = {0.f,0.f,0.f,0.f};
      #pragma unroll
      for (int s = 0; s < 16; s++){
        float dA = EXP2RAW(dt*al2[s]);
        h[s] = h[s]*dA + dtu*sBC[t][s];
        ap[s>>2] += h[s]*sBC[t][16+s];
      }
      float accv = (ap[0]+ap[1]) + (ap[2]+ap[3]);
      float yv = (accv + uu*Dc) * (zz * sigmoidf_(zz));
      yp[t*DIM] = f2bf(yv);
    }
  }
}

// ---------------- GCN aggregation ----------------
__global__ __launch_bounds__(192) void k_aggregate(
    const unsigned short* __restrict__ h, const int* __restrict__ row_ptr,
    const int* __restrict__ csr_src, const float* __restrict__ normS,
    const float* __restrict__ normD, unsigned short* __restrict__ m)
{
  int d = blockIdx.x; int tid = threadIdx.x;
  int e0 = row_ptr[d], e1 = row_ptr[d+1];
  float a0 = 0.f, a1 = 0.f, a2 = 0.f, a3 = 0.f;
  for (int e = e0; e < e1; e++){
    int sI = csr_src[e];
    float ns = normS[sI];
    uint2 v = *((const uint2*)(h + (size_t)sI*DF) + tid);
    a0 += bf2f((unsigned short)(v.x & 0xffff)) * ns;
    a1 += bf2f((unsigned short)(v.x >> 16)) * ns;
    a2 += bf2f((unsigned short)(v.y & 0xffff)) * ns;
    a3 += bf2f((unsigned short)(v.y >> 16)) * ns;
  }
  float nd = normD[d];
  uint2 o;
  o.x = (unsigned int)f2bf(a0*nd) | ((unsigned int)f2bf(a1*nd) << 16);
  o.y = (unsigned int)f2bf(a2*nd) | ((unsigned int)f2bf(a3*nd) << 16);
  *((uint2*)(m + (size_t)d*DF) + tid) = o;
}

// ---------------- finals ----------------
__global__ __launch_bounds__(256) void k_causal(const unsigned short* __restrict__ h,
                                                const float* __restrict__ W_c,
                                                const float* __restrict__ b_c,
                                                float* __restrict__ out){
  int wv = threadIdx.x >> 6, lane = threadIdx.x & 63;
  int r = blockIdx.x*4 + wv;
  float s = 0.f;
  #pragma unroll
  for (int j = 0; j < 12; j++){
    int cidx = lane + 64*j;
    s += bf2f(h[(size_t)r*DF + cidx]) * W_c[cidx];
  }
  s += __shfl_xor(s, 32); s += __shfl_xor(s, 16); s += __shfl_xor(s, 8);
  s += __shfl_xor(s, 4);  s += __shfl_xor(s, 2);  s += __shfl_xor(s, 1);
  if (lane == 0){
    float a = s + b_c[0];
    float cz = sigmoidf_(a);
    out[DF + r] = cz;
    out[DF + NN + r] = (cz > 0.7f) ? 1.f : 0.f;
  }
}

__global__ void k_gfeat(const unsigned short* __restrict__ h, float* __restrict__ out){
  int col = blockIdx.x*256 + threadIdx.x;
  int r0 = blockIdx.y * 512;
  float s = 0.f;
  for (int r = r0; r < r0 + 512; r++) s += bf2f(h[(size_t)r*DF + col]);
  atomicAdd(&out[col], s * (1.f/8192.f));
}

// ---------------- launch ----------------
extern "C" void kernel_launch(void* const* d_in, const int* in_sizes, int n_in,
                              void* d_out, int out_size, void* d_ws, size_t ws_size,
                              hipStream_t stream) {
  const float* node_feats = (const float*)d_in[0];
  const int*   timestamps = (const int*)d_in[1];
  const int*   ei         = (const int*)d_in[2];
  const int*   e_src = ei;
  const int*   e_dst = ei + NE_;
  const float* W_in    = (const float*)d_in[3];
  const float* conv_w  = (const float*)d_in[4];
  const float* conv_b  = (const float*)d_in[5];
  const float* W_xproj = (const float*)d_in[6];
  const float* W_dt    = (const float*)d_in[7];
  const float* b_dt    = (const float*)d_in[8];
  const float* A_log   = (const float*)d_in[9];
  const float* D_param = (const float*)d_in[10];
  const float* W_out   = (const float*)d_in[11];
  const float* Wg      = (const float*)d_in[12];
  const float* bg      = (const float*)d_in[13];
  const float* W_c     = (const float*)d_in[14];
  const float* b_c     = (const float*)d_in[15];
  float* out = (float*)d_out;

  char* ws = (char*)d_ws;
  size_t off = 0;
  auto alloc = [&](size_t bytes) -> char* {
    char* p = ws + off; off += (bytes + 255) & ~(size_t)255; return p;
  };
  unsigned short* WinT   = (unsigned short*)alloc((size_t)3072*768*2);
  unsigned short* WxT    = (unsigned short*)alloc((size_t)128*1536*2);
  unsigned short* WdtT   = (unsigned short*)alloc((size_t)1536*64*2);
  unsigned short* WoutT  = (unsigned short*)alloc((size_t)768*1536*2);
  unsigned short* WgT    = (unsigned short*)alloc((size_t)3*768*768*2);
  unsigned short* seq    = (unsigned short*)alloc((size_t)NN*DF*2);
  unsigned short* xz     = (unsigned short*)alloc((size_t)NN*3072*2);
  unsigned short* ubuf   = (unsigned short*)alloc((size_t)NN*DIM*2);
  float*          dbc    = (float*)alloc((size_t)NN*128*4);
  unsigned short* dt48   = (unsigned short*)alloc((size_t)NN*64*2);
  float*          deltaB = (float*)alloc((size_t)NN*DIM*4);
  unsigned short* ybuf   = (unsigned short*)alloc((size_t)NN*DIM*2);
  unsigned short* hbuf   = (unsigned short*)alloc((size_t)NN*DF*2);
  unsigned short* mbuf   = (unsigned short*)alloc((size_t)NN*DF*2);
  int*   pos    = (int*)alloc((size_t)NN*4);
  int*   degS   = (int*)alloc((size_t)2*NN*4);
  int*   degD   = degS + NN;
  float* normS  = (float*)alloc((size_t)NN*4);
  float* normD  = (float*)alloc((size_t)NN*4);
  int*   rowp   = (int*)alloc((size_t)(NN+1)*4);
  int*   cursor = (int*)alloc((size_t)NN*4);
  int*   csr    = (int*)alloc((size_t)NE_*4);

  // scan chunk summaries (12.58 MB each): hend aliases seq (dead after G1);
  // aprod aliases mbuf (first written by k_aggregate, after the scan)
  float* hend  = (float*)seq;
  float* aprod = (float*)mbuf;

  // zero-init accumulated buffers every call (harness poisons ws/d_out once)
  hipMemsetAsync(degS, 0, (size_t)2*NN*4, stream);
  hipMemsetAsync(pos, 0, (size_t)NN*4, stream);
  hipMemsetAsync(out, 0, (size_t)DF*4, stream);

  // weights: transpose+cast (B operands stored N x K row-major, zero-padded)
  k_transpose_cast<<<dim3(3, 3072), 256, 0, stream>>>(W_in, WinT, 768, 3072, 768);
  k_transpose_cast<<<dim3(6, 128),  256, 0, stream>>>(W_xproj, WxT, 1536, 80, 1536);
  k_transpose_cast<<<dim3(1, 1536), 256, 0, stream>>>(W_dt, WdtT, 48, 1536, 64);
  k_transpose_cast<<<dim3(6, 768),  256, 0, stream>>>(W_out, WoutT, 1536, 768, 1536);
  for (int i = 0; i < 3; i++)
    k_transpose_cast<<<dim3(3, 768), 256, 0, stream>>>(Wg + (size_t)i*768*768, WgT + (size_t)i*768*768, 768, 768, 768);

  // sort + gather (rank 2D-parallel: 32x32 blocks)
  k_rank<<<dim3(NN/256, NN/256), 256, 0, stream>>>(timestamps, pos);
  k_gather<<<NN, 256, 0, stream>>>(node_feats, pos, seq);

  // graph structure
  k_deg_count<<<NE_/256, 256, 0, stream>>>(e_src, e_dst, degS, degD);
  k_norms<<<NN/256, 256, 0, stream>>>(degS, degD, normS, normD);
  k_rowptr<<<1, 1024, 0, stream>>>(degD, rowp, cursor);
  k_csr_fill<<<NE_/256, 256, 0, stream>>>(e_src, e_dst, cursor, csr);

  // G1: xz = seq @ W_in  (8192x3072, K=768)
  k_gemm<0><<<64*24, 256, 0, stream>>>(seq, WinT, 3072, 768, 768, 768,
                                       nullptr, 0, xz, 3072, nullptr, nullptr);
  // conv + silu -> u
  k_conv_silu<<<dim3(6, NN), 256, 0, stream>>>(xz, conv_w, conv_b, ubuf);
  // G2: dbc = u @ W_xproj  (8192x128pad, K=1536); also dt48 bf16 (cols<48)
  k_gemm<1><<<64*1, 256, 0, stream>>>(ubuf, WxT, 128, 1536, 1536, 1536,
                                      dbc, 128, nullptr, 0, nullptr, dt48);
  // G3: delta = softplus(dt48 @ W_dt + b_dt)  (8192x1536, K=64)
  k_gemm<2><<<64*12, 256, 0, stream>>>(dt48, WdtT, 1536, 64, 64, 64,
                                       deltaB, 1536, nullptr, 0, b_dt, nullptr);
  // chunked scan -> y (fused (y + u*D)*silu(z))
  k_scanA<<<dim3(DIM/256, NCH), 256, 0, stream>>>(deltaB, ubuf, dbc, A_log, hend, aprod);
  k_scanB<<<96, 256, 0, stream>>>(hend, aprod);
  k_scanC<<<dim3(DIM/256, NCH), 256, 0, stream>>>(deltaB, ubuf, xz, dbc, A_log, D_param, hend, ybuf);
  // G4: h = y @ W_out  (8192x768, K=1536)
  k_gemm<0><<<64*6, 256, 0, stream>>>(ybuf, WoutT, 768, 1536, 1536, 1536,
                                      nullptr, 0, hbuf, 768, nullptr, nullptr);
  // 3 GCN layers
  for (int i = 0; i < 3; i++){
    k_aggregate<<<NN, 192, 0, stream>>>(hbuf, rowp, csr, normS, normD, mbuf);
    k_gemm<3><<<64*6, 256, 0, stream>>>(mbuf, WgT + (size_t)i*768*768, 768, 768, 768, 768,
                                        nullptr, 0, hbuf, 768, bg + (size_t)i*768, nullptr);
  }
  // finals
  k_causal<<<NN/4, 256, 0, stream>>>(hbuf, W_c, b_c, out);
  k_gfeat<<<dim3(3, 16), 256, 0, stream>>>(hbuf, out);
}

// Round 15
// 730.299 us; speedup vs baseline: 1.1584x; 1.0496x over previous
//
#include <hip/hip_runtime.h>
#include <math.h>

#define NN 8192
#define DF 768
#define NE_ 262144
#define DIM 1536
#define DSN 16
#define NCH 128
#define CL  64   // NN / NCH

typedef short short8 __attribute__((ext_vector_type(8)));
typedef float f32x4 __attribute__((ext_vector_type(4)));

__device__ __forceinline__ float bf2f(unsigned short u){
  unsigned int v = ((unsigned int)u) << 16; float f; __builtin_memcpy(&f, &v, 4); return f;
}
__device__ __forceinline__ unsigned short f2bf(float f){
  unsigned int x; __builtin_memcpy(&x, &f, 4);
  x += 0x7fffu + ((x >> 16) & 1u);
  return (unsigned short)(x >> 16);
}
__device__ __forceinline__ float sigmoidf_(float x){ return 1.f/(1.f+expf(-x)); }
#define EXP2RAW(x) __builtin_amdgcn_exp2f(x)   // single v_exp_f32
#define LOG2E 1.44269504088896f

// async global->LDS, 16B per lane; LDS dest is wave-uniform base + lane*16
__device__ __forceinline__ void gl_lds16(const unsigned short* g, unsigned short* l){
  __builtin_amdgcn_global_load_lds(
      (const __attribute__((address_space(1))) unsigned int*)g,
      (__attribute__((address_space(3))) unsigned int*)l,
      16, 0, 0);
}

// ---------------- fused weight prep: all transpose+cast in ONE launch ----------------
// out[n*Kp+k] = bf16(in[k*N+n]), zero-padded. Segment boundaries all multiples of 256.
__global__ __launch_bounds__(256) void k_prep(
    const float* __restrict__ W_in, const float* __restrict__ W_xproj,
    const float* __restrict__ W_dt, const float* __restrict__ W_out,
    const float* __restrict__ Wg,
    unsigned short* __restrict__ WinT, unsigned short* __restrict__ WxT,
    unsigned short* __restrict__ WdtT, unsigned short* __restrict__ WoutT,
    unsigned short* __restrict__ WgT)
{
  int b = blockIdx.x;
  const float* in; unsigned short* out; int K, N, Kp; long base;
  if (b < 9216)      { in = W_in;    out = WinT;  K = 768;  N = 3072; Kp = 768;  base = 0; }
  else if (b < 9984) { in = W_xproj; out = WxT;   K = 1536; N = 80;   Kp = 1536; base = (long)9216*256; }
  else if (b < 10368){ in = W_dt;    out = WdtT;  K = 48;   N = 1536; Kp = 64;   base = (long)9984*256; }
  else if (b < 14976){ in = W_out;   out = WoutT; K = 1536; N = 768;  Kp = 1536; base = (long)10368*256; }
  else {
    int g = (b - 14976) / 2304;
    in = Wg + (size_t)g*768*768; out = WgT + (size_t)g*768*768;
    K = 768; N = 768; Kp = 768; base = (long)(14976 + g*2304)*256;
  }
  long off = (long)b*256 + threadIdx.x - base;
  int n = (int)(off / Kp), k = (int)(off % Kp);
  unsigned short v = 0;
  if (k < K && n < N) v = f2bf(in[(size_t)k*N + n]);
  out[off] = v;
}

// ---------------- prep kernels ----------------

// stable rank, 2D-parallel
__global__ __launch_bounds__(256) void k_rank(const int* __restrict__ ts, int* __restrict__ pos){
  __shared__ int sT[256];
  int i = blockIdx.x*256 + threadIdx.x;
  int my = ts[i];
  int c0 = blockIdx.y*256;
  sT[threadIdx.x] = ts[c0 + threadIdx.x];
  __syncthreads();
  int r = 0;
  #pragma unroll 8
  for (int j = 0; j < 256; j++){
    int t = sT[j]; int jj = c0 + j;
    r += (t < my || (t == my && jj < i)) ? 1 : 0;
  }
  atomicAdd(&pos[i], r);
}

__global__ void k_gather(const float* __restrict__ nf, const int* __restrict__ pos,
                         unsigned short* __restrict__ seq){
  int i = blockIdx.x; int p = pos[i];
  const float* src = nf + (size_t)i*DF;
  unsigned short* dst = seq + (size_t)p*DF;
  for (int j = threadIdx.x; j < DF; j += 256) dst[j] = f2bf(src[j]);
}

__global__ void k_deg_count(const int* __restrict__ esrc, const int* __restrict__ edst,
                            int* __restrict__ degS, int* __restrict__ degD){
  int e = blockIdx.x*256 + threadIdx.x;
  if (e < NE_){ atomicAdd(&degS[esrc[e]], 1); atomicAdd(&degD[edst[e]], 1); }
}

__global__ void k_norms(const int* __restrict__ degS, const int* __restrict__ degD,
                        float* __restrict__ normS, float* __restrict__ normD){
  int i = blockIdx.x*256 + threadIdx.x;
  if (i < NN){
    normS[i] = rsqrtf(fmaxf((float)degS[i], 1.f));
    normD[i] = rsqrtf(fmaxf((float)degD[i], 1.f));
  }
}

__global__ __launch_bounds__(1024) void k_rowptr(const int* __restrict__ degD,
                                                 int* __restrict__ row_ptr, int* __restrict__ cursor){
  __shared__ int sp[1024];
  int tid = threadIdx.x;
  int base = tid*8;
  int loc[8]; int s = 0;
  #pragma unroll
  for (int j = 0; j < 8; j++){ loc[j] = degD[base+j]; s += loc[j]; }
  sp[tid] = s; __syncthreads();
  for (int o = 1; o < 1024; o <<= 1){
    int v = (tid >= o) ? sp[tid-o] : 0; __syncthreads();
    sp[tid] += v; __syncthreads();
  }
  int run = sp[tid] - s;   // exclusive
  #pragma unroll
  for (int j = 0; j < 8; j++){ row_ptr[base+j] = run; cursor[base+j] = run; run += loc[j]; }
  if (tid == 1023) row_ptr[NN] = sp[1023];
}

__global__ void k_csr_fill(const int* __restrict__ esrc, const int* __restrict__ edst,
                           int* __restrict__ cursor, int* __restrict__ csr_src){
  int e = blockIdx.x*256 + threadIdx.x;
  if (e < NE_){
    int d = edst[e];
    int p = atomicAdd(&cursor[d], 1);
    csr_src[p] = esrc[e];
  }
}

// ---------------- bf16 MFMA GEMM (128x128 tile, BK=64, 4 waves) ----------------
// Staging via global_load_lds width=16; two [128][32] sub-tiles per operand per
// K-iteration (k-halves), so ds_read pattern matches the proven BK=32 layout
// while halving barrier/drain count. K must be a multiple of 64.
template<int EPI>
__global__ __launch_bounds__(256) void k_gemm(
    const unsigned short* __restrict__ A, const unsigned short* __restrict__ B,
    int N, int K, int lda, int ldb,
    float* __restrict__ outF, int ldoF,
    unsigned short* __restrict__ outB, int ldoB,
    const float* __restrict__ bias,
    unsigned short* __restrict__ out2)
{
  __shared__ unsigned short sA[2][128*32];
  __shared__ unsigned short sB[2][128*32];
  int tid = threadIdx.x;
  int tnc = N >> 7;
  int bm = (blockIdx.x / tnc) << 7;
  int bn = (blockIdx.x % tnc) << 7;
  int wv = tid >> 6, lane = tid & 63;
  int wm = wv >> 1, wn = wv & 1;
  int l15 = lane & 15, l4 = lane >> 4;

  f32x4 acc[4][4];
  #pragma unroll
  for (int i = 0; i < 4; i++)
    #pragma unroll
    for (int j = 0; j < 4; j++)
      acc[i][j] = (f32x4){0.f,0.f,0.f,0.f};

  // staging geometry: per sub-tile, wave wv covers 16-row chunks wv*2, wv*2+1;
  // lane l -> row chunk*16 + (l>>2), col (l&3)*8 (16B)
  int r0 = (wv*2)*16 + (lane >> 2);
  int r1 = r0 + 16;
  int cc = (lane & 3)*8;
  const unsigned short* gA0 = A + (size_t)(bm + r0)*lda + cc;
  const unsigned short* gA1 = A + (size_t)(bm + r1)*lda + cc;
  const unsigned short* gB0 = B + (size_t)(bn + r0)*ldb + cc;
  const unsigned short* gB1 = B + (size_t)(bn + r1)*ldb + cc;
  unsigned short* lA0 = &sA[0][(size_t)(wv*2)*512];
  unsigned short* lA1 = &sA[1][(size_t)(wv*2)*512];
  unsigned short* lB0 = &sB[0][(size_t)(wv*2)*512];
  unsigned short* lB1 = &sB[1][(size_t)(wv*2)*512];

  for (int k0 = 0; k0 < K; k0 += 64){
    __syncthreads();     // all waves done reading previous tile
    gl_lds16(gA0 + k0,      lA0);
    gl_lds16(gA1 + k0,      lA0 + 512);
    gl_lds16(gA0 + k0 + 32, lA1);
    gl_lds16(gA1 + k0 + 32, lA1 + 512);
    gl_lds16(gB0 + k0,      lB0);
    gl_lds16(gB1 + k0,      lB0 + 512);
    gl_lds16(gB0 + k0 + 32, lB1);
    gl_lds16(gB1 + k0 + 32, lB1 + 512);
    __syncthreads();     // vmcnt(0) drained -> both k-halves ready
    #pragma unroll
    for (int h = 0; h < 2; h++){
      short8 af[4], bf_[4];
      #pragma unroll
      for (int i = 0; i < 4; i++){
        af[i]  = *(const short8*)&sA[h][(wm*64 + i*16 + l15)*32 + l4*8];
        bf_[i] = *(const short8*)&sB[h][(wn*64 + i*16 + l15)*32 + l4*8];
      }
      #pragma unroll
      for (int i = 0; i < 4; i++)
        #pragma unroll
        for (int j = 0; j < 4; j++)
          acc[i][j] = __builtin_amdgcn_mfma_f32_16x16x32_bf16(af[i], bf_[j], acc[i][j], 0, 0, 0);
    }
  }

  #pragma unroll
  for (int i = 0; i < 4; i++)
    #pragma unroll
    for (int j = 0; j < 4; j++)
      #pragma unroll
      for (int rr = 0; rr < 4; rr++){
        int row = bm + wm*64 + i*16 + l4*4 + rr;
        int col = bn + wn*64 + j*16 + l15;
        float v = acc[i][j][rr];
        if (EPI == 0){
          outB[(size_t)row*ldoB + col] = f2bf(v);
        } else if (EPI == 1){
          outF[(size_t)row*ldoF + col] = v;
          if (col < 64) out2[(size_t)row*64 + col] = (col < 48) ? f2bf(v) : (unsigned short)0;
        } else if (EPI == 2){
          v += bias[col];
          float sp = (v > 20.f) ? v : log1pf(expf(v));
          outF[(size_t)row*ldoF + col] = sp;
        } else {
          v += bias[col];
          float g = 0.5f*v*(1.f + erff(v*0.70710678118f));
          outB[(size_t)row*ldoB + col] = f2bf(g);
        }
      }
}

// ---------------- causal conv + silu ----------------
__global__ void k_conv_silu(const unsigned short* __restrict__ xz, const float* __restrict__ conv_w,
                            const float* __restrict__ conv_b, unsigned short* __restrict__ u){
  int c = blockIdx.x*256 + threadIdx.x;  // 0..1535
  int t = blockIdx.y;
  float acc = conv_b[c];
  #pragma unroll
  for (int k = 0; k < 4; k++){
    int tt = t - 3 + k;
    if (tt >= 0) acc += bf2f(xz[(size_t)tt*3072 + c]) * conv_w[c*4 + k];
  }
  u[(size_t)t*DIM + c] = f2bf(acc * sigmoidf_(acc));
}

// ---------------- selective scan: chunked parallel + power-chain exp ----------------
__device__ __forceinline__ void pow_tree(float e1, float dA[16]){
  float e2 = e1*e1, e4 = e2*e2, e8 = e4*e4;
  dA[0]=e1;      dA[1]=e2;      dA[2]=e2*e1;   dA[3]=e4;
  dA[4]=e4*e1;   dA[5]=e4*e2;   dA[6]=e4*dA[2];dA[7]=e8;
  dA[8]=e8*e1;   dA[9]=e8*e2;   dA[10]=e8*dA[2];dA[11]=e8*e4;
  dA[12]=e8*dA[4];dA[13]=e8*dA[5];dA[14]=e8*dA[6];dA[15]=e8*e8;
}

__global__ __launch_bounds__(256) void k_scanA(
    const float* __restrict__ delta, const unsigned short* __restrict__ u,
    const float* __restrict__ dbc, const float* __restrict__ A_log,
    float* __restrict__ hend, float* __restrict__ aprod)
{
  __shared__ float sBC[CL][32];   // [t][0:16]=B, [16:32]=C
  int tid = threadIdx.x;
  int c = blockIdx.x*256 + tid;
  int k = blockIdx.y;
  float al2[16];
  #pragma unroll
  for (int s = 0; s < 16; s++) al2[s] = -expf(A_log[(size_t)c*16 + s]) * LOG2E;
  bool fast = true;
  #pragma unroll
  for (int s = 1; s < 16; s++)
    fast = fast && (fabsf(al2[s] - (float)(s+1)*al2[0]) <= 1e-4f*fabsf(al2[s]));
  float h[16];
  #pragma unroll
  for (int s = 0; s < 16; s++) h[s] = 0.f;
  float sdt = 0.f;
  for (int idx = tid; idx < CL*32; idx += 256){
    int t = idx >> 5, j = idx & 31;
    sBC[t][j] = dbc[(size_t)(k*CL + t)*128 + 48 + j];
  }
  __syncthreads();
  const float* dp = delta + (size_t)k*CL*DIM + c;
  const unsigned short* up = u + (size_t)k*CL*DIM + c;
  if (fast){
    for (int t = 0; t < CL; t++){
      float dt = dp[t*DIM];
      float uu = bf2f(up[t*DIM]);
      float dtu = dt*uu;
      sdt += dt;
      float dA[16];
      pow_tree(EXP2RAW(dt*al2[0]), dA);
      #pragma unroll
      for (int s = 0; s < 16; s++)
        h[s] = h[s]*dA[s] + dtu*sBC[t][s];
    }
  } else {
    for (int t = 0; t < CL; t++){
      float dt = dp[t*DIM];
      float uu = bf2f(up[t*DIM]);
      float dtu = dt*uu;
      sdt += dt;
      #pragma unroll
      for (int s = 0; s < 16; s++){
        float dA = EXP2RAW(dt*al2[s]);
        h[s] = h[s]*dA + dtu*sBC[t][s];
      }
    }
  }
  size_t base = ((size_t)k*DIM + c)*16;
  #pragma unroll
  for (int s = 0; s < 16; s += 4){
    *(f32x4*)&hend[base+s]  = (f32x4){h[s],h[s+1],h[s+2],h[s+3]};
    *(f32x4*)&aprod[base+s] = (f32x4){EXP2RAW(al2[s]*sdt),EXP2RAW(al2[s+1]*sdt),
                                      EXP2RAW(al2[s+2]*sdt),EXP2RAW(al2[s+3]*sdt)};
  }
}

__global__ __launch_bounds__(256) void k_scanB(float* __restrict__ hend, const float* __restrict__ aprod){
  int i = blockIdx.x*256 + threadIdx.x;  // 0..24575 = (c,s) flat
  float H = 0.f;
  for (int k = 0; k < NCH; k++){
    size_t o = (size_t)k*DIM*16 + i;
    float e = hend[o], ap = aprod[o];
    hend[o] = H;          // incoming state for chunk k
    H = e + ap*H;         // exact linear-recurrence composition
  }
}

__global__ __launch_bounds__(256) void k_scanC(
    const float* __restrict__ delta, const unsigned short* __restrict__ u,
    const unsigned short* __restrict__ xz, const float* __restrict__ dbc,
    const float* __restrict__ A_log, const float* __restrict__ D_param,
    const float* __restrict__ hin, unsigned short* __restrict__ y)
{
  __shared__ float sBC[CL][32];
  int tid = threadIdx.x;
  int c = blockIdx.x*256 + tid;
  int k = blockIdx.y;
  float al2[16];
  #pragma unroll
  for (int s = 0; s < 16; s++) al2[s] = -expf(A_log[(size_t)c*16 + s]) * LOG2E;
  bool fast = true;
  #pragma unroll
  for (int s = 1; s < 16; s++)
    fast = fast && (fabsf(al2[s] - (float)(s+1)*al2[0]) <= 1e-4f*fabsf(al2[s]));
  float Dc = D_param[c];
  float h[16];
  size_t base = ((size_t)k*DIM + c)*16;
  #pragma unroll
  for (int s = 0; s < 16; s += 4){
    f32x4 v = *(const f32x4*)&hin[base+s];
    h[s] = v.x; h[s+1] = v.y; h[s+2] = v.z; h[s+3] = v.w;
  }
  for (int idx = tid; idx < CL*32; idx += 256){
    int t = idx >> 5, j = idx & 31;
    sBC[t][j] = dbc[(size_t)(k*CL + t)*128 + 48 + j];
  }
  __syncthreads();
  const float* dp = delta + (size_t)k*CL*DIM + c;
  const unsigned short* up = u + (size_t)k*CL*DIM + c;
  const unsigned short* zp = xz + (size_t)k*CL*3072 + 1536 + c;
  unsigned short* yp = y + (size_t)k*CL*DIM + c;
  if (fast){
    for (int t = 0; t < CL; t++){
      float dt = dp[t*DIM];
      float uu = bf2f(up[t*DIM]);
      float zz = bf2f(zp[t*3072]);
      float dtu = dt*uu;
      float dA[16];
      pow_tree(EXP2RAW(dt*al2[0]), dA);
      float ap[4] = {0.f,0.f,0.f,0.f};
      #pragma unroll
      for (int s = 0; s < 16; s++){
        h[s] = h[s]*dA[s] + dtu*sBC[t][s];
        ap[s>>2] += h[s]*sBC[t][16+s];
      }
      float accv = (ap[0]+ap[1]) + (ap[2]+ap[3]);
      float yv = (accv + uu*Dc) * (zz * sigmoidf_(zz));
      yp[t*DIM] = f2bf(yv);
    }
  } else {
    for (int t = 0; t < CL; t++){
      float dt = dp[t*DIM];
      float uu = bf2f(up[t*DIM]);
      float zz = bf2f(zp[t*3072]);
      float dtu = dt*uu;
      float ap[4] = {0.f,0.f,0.f,0.f};
      #pragma unroll
      for (int s = 0; s < 16; s++){
        float dA = EXP2RAW(dt*al2[s]);
        h[s] = h[s]*dA + dtu*sBC[t][s];
        ap[s>>2] += h[s]*sBC[t][16+s];
      }
      float accv = (ap[0]+ap[1]) + (ap[2]+ap[3]);
      float yv = (accv + uu*Dc) * (zz * sigmoidf_(zz));
      yp[t*DIM] = f2bf(yv);
    }
  }
}

// ---------------- GCN aggregation ----------------
__global__ __launch_bounds__(192) void k_aggregate(
    const unsigned short* __restrict__ h, const int* __restrict__ row_ptr,
    const int* __restrict__ csr_src, const float* __restrict__ normS,
    const float* __restrict__ normD, unsigned short* __restrict__ m)
{
  int d = blockIdx.x; int tid = threadIdx.x;
  int e0 = row_ptr[d], e1 = row_ptr[d+1];
  float a0 = 0.f, a1 = 0.f, a2 = 0.f, a3 = 0.f;
  for (int e = e0; e < e1; e++){
    int sI = csr_src[e];
    float ns = normS[sI];
    uint2 v = *((const uint2*)(h + (size_t)sI*DF) + tid);
    a0 += bf2f((unsigned short)(v.x & 0xffff)) * ns;
    a1 += bf2f((unsigned short)(v.x >> 16)) * ns;
    a2 += bf2f((unsigned short)(v.y & 0xffff)) * ns;
    a3 += bf2f((unsigned short)(v.y >> 16)) * ns;
  }
  float nd = normD[d];
  uint2 o;
  o.x = (unsigned int)f2bf(a0*nd) | ((unsigned int)f2bf(a1*nd) << 16);
  o.y = (unsigned int)f2bf(a2*nd) | ((unsigned int)f2bf(a3*nd) << 16);
  *((uint2*)(m + (size_t)d*DF) + tid) = o;
}

// ---------------- finals ----------------
__global__ __launch_bounds__(256) void k_causal(const unsigned short* __restrict__ h,
                                                const float* __restrict__ W_c,
                                                const float* __restrict__ b_c,
                                                float* __restrict__ out){
  int wv = threadIdx.x >> 6, lane = threadIdx.x & 63;
  int r = blockIdx.x*4 + wv;
  float s = 0.f;
  #pragma unroll
  for (int j = 0; j < 12; j++){
    int cidx = lane + 64*j;
    s += bf2f(h[(size_t)r*DF + cidx]) * W_c[cidx];
  }
  s += __shfl_xor(s, 32); s += __shfl_xor(s, 16); s += __shfl_xor(s, 8);
  s += __shfl_xor(s, 4);  s += __shfl_xor(s, 2);  s += __shfl_xor(s, 1);
  if (lane == 0){
    float a = s + b_c[0];
    float cz = sigmoidf_(a);
    out[DF + r] = cz;
    out[DF + NN + r] = (cz > 0.7f) ? 1.f : 0.f;
  }
}

__global__ void k_gfeat(const unsigned short* __restrict__ h, float* __restrict__ out){
  int col = blockIdx.x*256 + threadIdx.x;
  int r0 = blockIdx.y * 512;
  float s = 0.f;
  for (int r = r0; r < r0 + 512; r++) s += bf2f(h[(size_t)r*DF + col]);
  atomicAdd(&out[col], s * (1.f/8192.f));
}

// ---------------- launch ----------------
extern "C" void kernel_launch(void* const* d_in, const int* in_sizes, int n_in,
                              void* d_out, int out_size, void* d_ws, size_t ws_size,
                              hipStream_t stream) {
  const float* node_feats = (const float*)d_in[0];
  const int*   timestamps = (const int*)d_in[1];
  const int*   ei         = (const int*)d_in[2];
  const int*   e_src = ei;
  const int*   e_dst = ei + NE_;
  const float* W_in    = (const float*)d_in[3];
  const float* conv_w  = (const float*)d_in[4];
  const float* conv_b  = (const float*)d_in[5];
  const float* W_xproj = (const float*)d_in[6];
  const float* W_dt    = (const float*)d_in[7];
  const float* b_dt    = (const float*)d_in[8];
  const float* A_log   = (const float*)d_in[9];
  const float* D_param = (const float*)d_in[10];
  const float* W_out   = (const float*)d_in[11];
  const float* Wg      = (const float*)d_in[12];
  const float* bg      = (const float*)d_in[13];
  const float* W_c     = (const float*)d_in[14];
  const float* b_c     = (const float*)d_in[15];
  float* out = (float*)d_out;

  char* ws = (char*)d_ws;
  size_t off = 0;
  auto alloc = [&](size_t bytes) -> char* {
    char* p = ws + off; off += (bytes + 255) & ~(size_t)255; return p;
  };
  unsigned short* WinT   = (unsigned short*)alloc((size_t)3072*768*2);
  unsigned short* WxT    = (unsigned short*)alloc((size_t)128*1536*2);
  unsigned short* WdtT   = (unsigned short*)alloc((size_t)1536*64*2);
  unsigned short* WoutT  = (unsigned short*)alloc((size_t)768*1536*2);
  unsigned short* WgT    = (unsigned short*)alloc((size_t)3*768*768*2);
  unsigned short* seq    = (unsigned short*)alloc((size_t)NN*DF*2);
  unsigned short* xz     = (unsigned short*)alloc((size_t)NN*3072*2);
  unsigned short* ubuf   = (unsigned short*)alloc((size_t)NN*DIM*2);
  float*          dbc    = (float*)alloc((size_t)NN*128*4);
  unsigned short* dt48   = (unsigned short*)alloc((size_t)NN*64*2);
  float*          deltaB = (float*)alloc((size_t)NN*DIM*4);
  unsigned short* ybuf   = (unsigned short*)alloc((size_t)NN*DIM*2);
  unsigned short* hbuf   = (unsigned short*)alloc((size_t)NN*DF*2);
  unsigned short* mbuf   = (unsigned short*)alloc((size_t)NN*DF*2);
  int*   pos    = (int*)alloc((size_t)NN*4);
  int*   degS   = (int*)alloc((size_t)2*NN*4);
  int*   degD   = degS + NN;
  float* normS  = (float*)alloc((size_t)NN*4);
  float* normD  = (float*)alloc((size_t)NN*4);
  int*   rowp   = (int*)alloc((size_t)(NN+1)*4);
  int*   cursor = (int*)alloc((size_t)NN*4);
  int*   csr    = (int*)alloc((size_t)NE_*4);

  // scan chunk summaries (12.58 MB each): hend aliases seq (dead after G1);
  // aprod aliases mbuf (first written by k_aggregate, after the scan)
  float* hend  = (float*)seq;
  float* aprod = (float*)mbuf;

  // zero-init accumulated buffers every call (harness poisons ws/d_out once)
  hipMemsetAsync(degS, 0, (size_t)2*NN*4, stream);
  hipMemsetAsync(pos, 0, (size_t)NN*4, stream);
  hipMemsetAsync(out, 0, (size_t)DF*4, stream);

  // all weight transposes in one launch (segments sized at compile time)
  k_prep<<<21888, 256, 0, stream>>>(W_in, W_xproj, W_dt, W_out, Wg,
                                    WinT, WxT, WdtT, WoutT, WgT);

  // sort + gather (rank 2D-parallel: 32x32 blocks)
  k_rank<<<dim3(NN/256, NN/256), 256, 0, stream>>>(timestamps, pos);
  k_gather<<<NN, 256, 0, stream>>>(node_feats, pos, seq);

  // graph structure
  k_deg_count<<<NE_/256, 256, 0, stream>>>(e_src, e_dst, degS, degD);
  k_norms<<<NN/256, 256, 0, stream>>>(degS, degD, normS, normD);
  k_rowptr<<<1, 1024, 0, stream>>>(degD, rowp, cursor);
  k_csr_fill<<<NE_/256, 256, 0, stream>>>(e_src, e_dst, cursor, csr);

  // G1: xz = seq @ W_in  (8192x3072, K=768)
  k_gemm<0><<<64*24, 256, 0, stream>>>(seq, WinT, 3072, 768, 768, 768,
                                       nullptr, 0, xz, 3072, nullptr, nullptr);
  // conv + silu -> u
  k_conv_silu<<<dim3(6, NN), 256, 0, stream>>>(xz, conv_w, conv_b, ubuf);
  // G2: dbc = u @ W_xproj  (8192x128pad, K=1536); also dt48 bf16 (cols<48)
  k_gemm<1><<<64*1, 256, 0, stream>>>(ubuf, WxT, 128, 1536, 1536, 1536,
                                      dbc, 128, nullptr, 0, nullptr, dt48);
  // G3: delta = softplus(dt48 @ W_dt + b_dt)  (8192x1536, K=64)
  k_gemm<2><<<64*12, 256, 0, stream>>>(dt48, WdtT, 1536, 64, 64, 64,
                                       deltaB, 1536, nullptr, 0, b_dt, nullptr);
  // chunked scan -> y (fused (y + u*D)*silu(z))
  k_scanA<<<dim3(DIM/256, NCH), 256, 0, stream>>>(deltaB, ubuf, dbc, A_log, hend, aprod);
  k_scanB<<<96, 256, 0, stream>>>(hend, aprod);
  k_scanC<<<dim3(DIM/256, NCH), 256, 0, stream>>>(deltaB, ubuf, xz, dbc, A_log, D_param, hend, ybuf);
  // G4: h = y @ W_out  (8192x768, K=1536)
  k_gemm<0><<<64*6, 256, 0, stream>>>(ybuf, WoutT, 768, 1536, 1536, 1536,
                                      nullptr, 0, hbuf, 768, nullptr, nullptr);
  // 3 GCN layers
  for (int i = 0; i < 3; i++){
    k_aggregate<<<NN, 192, 0, stream>>>(hbuf, rowp, csr, normS, normD, mbuf);
    k_gemm<3><<<64*6, 256, 0, stream>>>(mbuf, WgT + (size_t)i*768*768, 768, 768, 768, 768,
                                        nullptr, 0, hbuf, 768, bg + (size_t)i*768, nullptr);
  }
  // finals
  k_causal<<<NN/4, 256, 0, stream>>>(hbuf, W_c, b_c, out);
  k_gfeat<<<dim3(3, 16), 256, 0, stream>>>(hbuf, out);
}

// Round 16
// 722.519 us; speedup vs baseline: 1.1708x; 1.0108x over previous
//
#include <hip/hip_runtime.h>
#include <math.h>

#define NN 8192
#define DF 768
#define NE_ 262144
#define DIM 1536
#define DSN 16
#define NCH 128
#define CL  64   // NN / NCH

typedef short short8 __attribute__((ext_vector_type(8)));
typedef float f32x4 __attribute__((ext_vector_type(4)));

__device__ __forceinline__ float bf2f(unsigned short u){
  unsigned int v = ((unsigned int)u) << 16; float f; __builtin_memcpy(&f, &v, 4); return f;
}
__device__ __forceinline__ unsigned short f2bf(float f){
  unsigned int x; __builtin_memcpy(&x, &f, 4);
  x += 0x7fffu + ((x >> 16) & 1u);
  return (unsigned short)(x >> 16);
}
__device__ __forceinline__ float sigmoidf_(float x){ return 1.f/(1.f+expf(-x)); }
#define EXP2RAW(x) __builtin_amdgcn_exp2f(x)   // single v_exp_f32
#define LOG2E 1.44269504088896f

// async global->LDS, 16B per lane; LDS dest is wave-uniform base + lane*16
__device__ __forceinline__ void gl_lds16(const unsigned short* g, unsigned short* l){
  __builtin_amdgcn_global_load_lds(
      (const __attribute__((address_space(1))) unsigned int*)g,
      (__attribute__((address_space(3))) unsigned int*)l,
      16, 0, 0);
}

// ---------------- fused weight prep: all transpose+cast in ONE launch ----------------
__global__ __launch_bounds__(256) void k_prep(
    const float* __restrict__ W_in, const float* __restrict__ W_xproj,
    const float* __restrict__ W_dt, const float* __restrict__ W_out,
    const float* __restrict__ Wg,
    unsigned short* __restrict__ WinT, unsigned short* __restrict__ WxT,
    unsigned short* __restrict__ WdtT, unsigned short* __restrict__ WoutT,
    unsigned short* __restrict__ WgT)
{
  int b = blockIdx.x;
  const float* in; unsigned short* out; int K, N, Kp; long base;
  if (b < 9216)      { in = W_in;    out = WinT;  K = 768;  N = 3072; Kp = 768;  base = 0; }
  else if (b < 9984) { in = W_xproj; out = WxT;   K = 1536; N = 80;   Kp = 1536; base = (long)9216*256; }
  else if (b < 10368){ in = W_dt;    out = WdtT;  K = 48;   N = 1536; Kp = 64;   base = (long)9984*256; }
  else if (b < 14976){ in = W_out;   out = WoutT; K = 1536; N = 768;  Kp = 1536; base = (long)10368*256; }
  else {
    int g = (b - 14976) / 2304;
    in = Wg + (size_t)g*768*768; out = WgT + (size_t)g*768*768;
    K = 768; N = 768; Kp = 768; base = (long)(14976 + g*2304)*256;
  }
  long off = (long)b*256 + threadIdx.x - base;
  int n = (int)(off / Kp), k = (int)(off % Kp);
  unsigned short v = 0;
  if (k < K && n < N) v = f2bf(in[(size_t)k*N + n]);
  out[off] = v;
}

// ---------------- prep kernels ----------------

__global__ __launch_bounds__(256) void k_rank(const int* __restrict__ ts, int* __restrict__ pos){
  __shared__ int sT[256];
  int i = blockIdx.x*256 + threadIdx.x;
  int my = ts[i];
  int c0 = blockIdx.y*256;
  sT[threadIdx.x] = ts[c0 + threadIdx.x];
  __syncthreads();
  int r = 0;
  #pragma unroll 8
  for (int j = 0; j < 256; j++){
    int t = sT[j]; int jj = c0 + j;
    r += (t < my || (t == my && jj < i)) ? 1 : 0;
  }
  atomicAdd(&pos[i], r);
}

__global__ void k_gather(const float* __restrict__ nf, const int* __restrict__ pos,
                         unsigned short* __restrict__ seq){
  int i = blockIdx.x; int p = pos[i];
  const float* src = nf + (size_t)i*DF;
  unsigned short* dst = seq + (size_t)p*DF;
  for (int j = threadIdx.x; j < DF; j += 256) dst[j] = f2bf(src[j]);
}

__global__ void k_deg_count(const int* __restrict__ esrc, const int* __restrict__ edst,
                            int* __restrict__ degS, int* __restrict__ degD){
  int e = blockIdx.x*256 + threadIdx.x;
  if (e < NE_){ atomicAdd(&degS[esrc[e]], 1); atomicAdd(&degD[edst[e]], 1); }
}

__global__ void k_norms(const int* __restrict__ degS, const int* __restrict__ degD,
                        float* __restrict__ normS, float* __restrict__ normD){
  int i = blockIdx.x*256 + threadIdx.x;
  if (i < NN){
    normS[i] = rsqrtf(fmaxf((float)degS[i], 1.f));
    normD[i] = rsqrtf(fmaxf((float)degD[i], 1.f));
  }
}

__global__ __launch_bounds__(1024) void k_rowptr(const int* __restrict__ degD,
                                                 int* __restrict__ row_ptr, int* __restrict__ cursor){
  __shared__ int sp[1024];
  int tid = threadIdx.x;
  int base = tid*8;
  int loc[8]; int s = 0;
  #pragma unroll
  for (int j = 0; j < 8; j++){ loc[j] = degD[base+j]; s += loc[j]; }
  sp[tid] = s; __syncthreads();
  for (int o = 1; o < 1024; o <<= 1){
    int v = (tid >= o) ? sp[tid-o] : 0; __syncthreads();
    sp[tid] += v; __syncthreads();
  }
  int run = sp[tid] - s;   // exclusive
  #pragma unroll
  for (int j = 0; j < 8; j++){ row_ptr[base+j] = run; cursor[base+j] = run; run += loc[j]; }
  if (tid == 1023) row_ptr[NN] = sp[1023];
}

__global__ void k_csr_fill(const int* __restrict__ esrc, const int* __restrict__ edst,
                           int* __restrict__ cursor, int* __restrict__ csr_src){
  int e = blockIdx.x*256 + threadIdx.x;
  if (e < NE_){
    int d = edst[e];
    int p = atomicAdd(&cursor[d], 1);
    csr_src[p] = esrc[e];
  }
}

// ---------------- bf16 MFMA GEMM (128x128 tile, BK=64, 4 waves) ----------------
// Staging via global_load_lds width=16; two [128][32] sub-tiles per operand per
// K-iteration. EPI 2 now writes softplus as bf16 (outB).
template<int EPI>
__global__ __launch_bounds__(256) void k_gemm(
    const unsigned short* __restrict__ A, const unsigned short* __restrict__ B,
    int N, int K, int lda, int ldb,
    float* __restrict__ outF, int ldoF,
    unsigned short* __restrict__ outB, int ldoB,
    const float* __restrict__ bias,
    unsigned short* __restrict__ out2)
{
  __shared__ unsigned short sA[2][128*32];
  __shared__ unsigned short sB[2][128*32];
  int tid = threadIdx.x;
  int tnc = N >> 7;
  int bm = (blockIdx.x / tnc) << 7;
  int bn = (blockIdx.x % tnc) << 7;
  int wv = tid >> 6, lane = tid & 63;
  int wm = wv >> 1, wn = wv & 1;
  int l15 = lane & 15, l4 = lane >> 4;

  f32x4 acc[4][4];
  #pragma unroll
  for (int i = 0; i < 4; i++)
    #pragma unroll
    for (int j = 0; j < 4; j++)
      acc[i][j] = (f32x4){0.f,0.f,0.f,0.f};

  int r0 = (wv*2)*16 + (lane >> 2);
  int r1 = r0 + 16;
  int cc = (lane & 3)*8;
  const unsigned short* gA0 = A + (size_t)(bm + r0)*lda + cc;
  const unsigned short* gA1 = A + (size_t)(bm + r1)*lda + cc;
  const unsigned short* gB0 = B + (size_t)(bn + r0)*ldb + cc;
  const unsigned short* gB1 = B + (size_t)(bn + r1)*ldb + cc;
  unsigned short* lA0 = &sA[0][(size_t)(wv*2)*512];
  unsigned short* lA1 = &sA[1][(size_t)(wv*2)*512];
  unsigned short* lB0 = &sB[0][(size_t)(wv*2)*512];
  unsigned short* lB1 = &sB[1][(size_t)(wv*2)*512];

  for (int k0 = 0; k0 < K; k0 += 64){
    __syncthreads();
    gl_lds16(gA0 + k0,      lA0);
    gl_lds16(gA1 + k0,      lA0 + 512);
    gl_lds16(gA0 + k0 + 32, lA1);
    gl_lds16(gA1 + k0 + 32, lA1 + 512);
    gl_lds16(gB0 + k0,      lB0);
    gl_lds16(gB1 + k0,      lB0 + 512);
    gl_lds16(gB0 + k0 + 32, lB1);
    gl_lds16(gB1 + k0 + 32, lB1 + 512);
    __syncthreads();
    #pragma unroll
    for (int h = 0; h < 2; h++){
      short8 af[4], bf_[4];
      #pragma unroll
      for (int i = 0; i < 4; i++){
        af[i]  = *(const short8*)&sA[h][(wm*64 + i*16 + l15)*32 + l4*8];
        bf_[i] = *(const short8*)&sB[h][(wn*64 + i*16 + l15)*32 + l4*8];
      }
      #pragma unroll
      for (int i = 0; i < 4; i++)
        #pragma unroll
        for (int j = 0; j < 4; j++)
          acc[i][j] = __builtin_amdgcn_mfma_f32_16x16x32_bf16(af[i], bf_[j], acc[i][j], 0, 0, 0);
    }
  }

  #pragma unroll
  for (int i = 0; i < 4; i++)
    #pragma unroll
    for (int j = 0; j < 4; j++)
      #pragma unroll
      for (int rr = 0; rr < 4; rr++){
        int row = bm + wm*64 + i*16 + l4*4 + rr;
        int col = bn + wn*64 + j*16 + l15;
        float v = acc[i][j][rr];
        if (EPI == 0){
          outB[(size_t)row*ldoB + col] = f2bf(v);
        } else if (EPI == 1){
          outF[(size_t)row*ldoF + col] = v;
          if (col < 64) out2[(size_t)row*64 + col] = (col < 48) ? f2bf(v) : (unsigned short)0;
        } else if (EPI == 2){
          v += bias[col];
          float sp = (v > 20.f) ? v : log1pf(expf(v));
          outB[(size_t)row*ldoB + col] = f2bf(sp);
        } else {
          v += bias[col];
          float g = 0.5f*v*(1.f + erff(v*0.70710678118f));
          outB[(size_t)row*ldoB + col] = f2bf(g);
        }
      }
}

// ---------------- causal conv + silu ----------------
__global__ void k_conv_silu(const unsigned short* __restrict__ xz, const float* __restrict__ conv_w,
                            const float* __restrict__ conv_b, unsigned short* __restrict__ u){
  int c = blockIdx.x*256 + threadIdx.x;  // 0..1535
  int t = blockIdx.y;
  float acc = conv_b[c];
  #pragma unroll
  for (int k = 0; k < 4; k++){
    int tt = t - 3 + k;
    if (tt >= 0) acc += bf2f(xz[(size_t)tt*3072 + c]) * conv_w[c*4 + k];
  }
  u[(size_t)t*DIM + c] = f2bf(acc * sigmoidf_(acc));
}

// ---------------- selective scan: chunked parallel + power-chain exp + prefetch ----------------
__device__ __forceinline__ void pow_tree(float e1, float dA[16]){
  float e2 = e1*e1, e4 = e2*e2, e8 = e4*e4;
  dA[0]=e1;      dA[1]=e2;      dA[2]=e2*e1;   dA[3]=e4;
  dA[4]=e4*e1;   dA[5]=e4*e2;   dA[6]=e4*dA[2];dA[7]=e8;
  dA[8]=e8*e1;   dA[9]=e8*e2;   dA[10]=e8*dA[2];dA[11]=e8*e4;
  dA[12]=e8*dA[4];dA[13]=e8*dA[5];dA[14]=e8*dA[6];dA[15]=e8*e8;
}

__global__ __launch_bounds__(256) void k_scanA(
    const unsigned short* __restrict__ delta, const unsigned short* __restrict__ u,
    const float* __restrict__ dbc, const float* __restrict__ A_log,
    float* __restrict__ hend, float* __restrict__ aprod)
{
  __shared__ float sBC[CL][32];   // [t][0:16]=B, [16:32]=C
  int tid = threadIdx.x;
  int c = blockIdx.x*256 + tid;
  int k = blockIdx.y;
  float al2[16];
  #pragma unroll
  for (int s = 0; s < 16; s++) al2[s] = -expf(A_log[(size_t)c*16 + s]) * LOG2E;
  bool fast = true;
  #pragma unroll
  for (int s = 1; s < 16; s++)
    fast = fast && (fabsf(al2[s] - (float)(s+1)*al2[0]) <= 1e-4f*fabsf(al2[s]));
  float h[16];
  #pragma unroll
  for (int s = 0; s < 16; s++) h[s] = 0.f;
  float sdt = 0.f;
  for (int idx = tid; idx < CL*32; idx += 256){
    int t = idx >> 5, j = idx & 31;
    sBC[t][j] = dbc[(size_t)(k*CL + t)*128 + 48 + j];
  }
  __syncthreads();
  const unsigned short* dp = delta + (size_t)k*CL*DIM + c;
  const unsigned short* up = u + (size_t)k*CL*DIM + c;
  unsigned short dtn = dp[0], uun = up[0];
  if (fast){
    #pragma unroll 2
    for (int t = 0; t < CL; t++){
      float dt = bf2f(dtn), uu = bf2f(uun);
      int tn = (t+1 < CL) ? t+1 : t;
      dtn = dp[tn*DIM]; uun = up[tn*DIM];
      float dtu = dt*uu;
      sdt += dt;
      float dA[16];
      pow_tree(EXP2RAW(dt*al2[0]), dA);
      #pragma unroll
      for (int s = 0; s < 16; s++)
        h[s] = h[s]*dA[s] + dtu*sBC[t][s];
    }
  } else {
    #pragma unroll 2
    for (int t = 0; t < CL; t++){
      float dt = bf2f(dtn), uu = bf2f(uun);
      int tn = (t+1 < CL) ? t+1 : t;
      dtn = dp[tn*DIM]; uun = up[tn*DIM];
      float dtu = dt*uu;
      sdt += dt;
      #pragma unroll
      for (int s = 0; s < 16; s++){
        float dA = EXP2RAW(dt*al2[s]);
        h[s] = h[s]*dA + dtu*sBC[t][s];
      }
    }
  }
  size_t base = ((size_t)k*DIM + c)*16;
  #pragma unroll
  for (int s = 0; s < 16; s += 4){
    *(f32x4*)&hend[base+s]  = (f32x4){h[s],h[s+1],h[s+2],h[s+3]};
    *(f32x4*)&aprod[base+s] = (f32x4){EXP2RAW(al2[s]*sdt),EXP2RAW(al2[s+1]*sdt),
                                      EXP2RAW(al2[s+2]*sdt),EXP2RAW(al2[s+3]*sdt)};
  }
}

__global__ __launch_bounds__(256) void k_scanB(float* __restrict__ hend, const float* __restrict__ aprod){
  int i = blockIdx.x*256 + threadIdx.x;  // 0..24575 = (c,s) flat
  float H = 0.f;
  for (int k = 0; k < NCH; k++){
    size_t o = (size_t)k*DIM*16 + i;
    float e = hend[o], ap = aprod[o];
    hend[o] = H;          // incoming state for chunk k
    H = e + ap*H;         // exact linear-recurrence composition
  }
}

__global__ __launch_bounds__(256) void k_scanC(
    const unsigned short* __restrict__ delta, const unsigned short* __restrict__ u,
    const unsigned short* __restrict__ xz, const float* __restrict__ dbc,
    const float* __restrict__ A_log, const float* __restrict__ D_param,
    const float* __restrict__ hin, unsigned short* __restrict__ y)
{
  __shared__ float sBC[CL][32];
  int tid = threadIdx.x;
  int c = blockIdx.x*256 + tid;
  int k = blockIdx.y;
  float al2[16];
  #pragma unroll
  for (int s = 0; s < 16; s++) al2[s] = -expf(A_log[(size_t)c*16 + s]) * LOG2E;
  bool fast = true;
  #pragma unroll
  for (int s = 1; s < 16; s++)
    fast = fast && (fabsf(al2[s] - (float)(s+1)*al2[0]) <= 1e-4f*fabsf(al2[s]));
  float Dc = D_param[c];
  float h[16];
  size_t base = ((size_t)k*DIM + c)*16;
  #pragma unroll
  for (int s = 0; s < 16; s += 4){
    f32x4 v = *(const f32x4*)&hin[base+s];
    h[s] = v.x; h[s+1] = v.y; h[s+2] = v.z; h[s+3] = v.w;
  }
  for (int idx = tid; idx < CL*32; idx += 256){
    int t = idx >> 5, j = idx & 31;
    sBC[t][j] = dbc[(size_t)(k*CL + t)*128 + 48 + j];
  }
  __syncthreads();
  const unsigned short* dp = delta + (size_t)k*CL*DIM + c;
  const unsigned short* up = u + (size_t)k*CL*DIM + c;
  const unsigned short* zp = xz + (size_t)k*CL*3072 + 1536 + c;
  unsigned short* yp = y + (size_t)k*CL*DIM + c;
  unsigned short dtn = dp[0], uun = up[0], zzn = zp[0];
  if (fast){
    #pragma unroll 2
    for (int t = 0; t < CL; t++){
      float dt = bf2f(dtn), uu = bf2f(uun), zz = bf2f(zzn);
      int tn = (t+1 < CL) ? t+1 : t;
      dtn = dp[tn*DIM]; uun = up[tn*DIM]; zzn = zp[tn*3072];
      float dtu = dt*uu;
      float dA[16];
      pow_tree(EXP2RAW(dt*al2[0]), dA);
      float ap[4] = {0.f,0.f,0.f,0.f};
      #pragma unroll
      for (int s = 0; s < 16; s++){
        h[s] = h[s]*dA[s] + dtu*sBC[t][s];
        ap[s>>2] += h[s]*sBC[t][16+s];
      }
      float accv = (ap[0]+ap[1]) + (ap[2]+ap[3]);
      float yv = (accv + uu*Dc) * (zz * sigmoidf_(zz));
      yp[t*DIM] = f2bf(yv);
    }
  } else {
    #pragma unroll 2
    for (int t = 0; t < CL; t++){
      float dt = bf2f(dtn), uu = bf2f(uun), zz = bf2f(zzn);
      int tn = (t+1 < CL) ? t+1 : t;
      dtn = dp[tn*DIM]; uun = up[tn*DIM]; zzn = zp[tn*3072];
      float dtu = dt*uu;
      float ap[4] = {0.f,0.f,0.f,0.f};
      #pragma unroll
      for (int s = 0; s < 16; s++){
        float dA = EXP2RAW(dt*al2[s]);
        h[s] = h[s]*dA + dtu*sBC[t][s];
        ap[s>>2] += h[s]*sBC[t][16+s];
      }
      float accv = (ap[0]+ap[1]) + (ap[2]+ap[3]);
      float yv = (accv + uu*Dc) * (zz * sigmoidf_(zz));
      yp[t*DIM] = f2bf(yv);
    }
  }
}

// ---------------- GCN aggregation ----------------
__global__ __launch_bounds__(192) void k_aggregate(
    const unsigned short* __restrict__ h, const int* __restrict__ row_ptr,
    const int* __restrict__ csr_src, const float* __restrict__ normS,
    const float* __restrict__ normD, unsigned short* __restrict__ m)
{
  int d = blockIdx.x; int tid = threadIdx.x;
  int e0 = row_ptr[d], e1 = row_ptr[d+1];
  float a0 = 0.f, a1 = 0.f, a2 = 0.f, a3 = 0.f;
  for (int e = e0; e < e1; e++){
    int sI = csr_src[e];
    float ns = normS[sI];
    uint2 v = *((const uint2*)(h + (size_t)sI*DF) + tid);
    a0 += bf2f((unsigned short)(v.x & 0xffff)) * ns;
    a1 += bf2f((unsigned short)(v.x >> 16)) * ns;
    a2 += bf2f((unsigned short)(v.y & 0xffff)) * ns;
    a3 += bf2f((unsigned short)(v.y >> 16)) * ns;
  }
  float nd = normD[d];
  uint2 o;
  o.x = (unsigned int)f2bf(a0*nd) | ((unsigned int)f2bf(a1*nd) << 16);
  o.y = (unsigned int)f2bf(a2*nd) | ((unsigned int)f2bf(a3*nd) << 16);
  *((uint2*)(m + (size_t)d*DF) + tid) = o;
}

// ---------------- finals ----------------
__global__ __launch_bounds__(256) void k_causal(const unsigned short* __restrict__ h,
                                                const float* __restrict__ W_c,
                                                const float* __restrict__ b_c,
                                                float* __restrict__ out){
  int wv = threadIdx.x >> 6, lane = threadIdx.x & 63;
  int r = blockIdx.x*4 + wv;
  float s = 0.f;
  #pragma unroll
  for (int j = 0; j < 12; j++){
    int cidx = lane + 64*j;
    s += bf2f(h[(size_t)r*DF + cidx]) * W_c[cidx];
  }
  s += __shfl_xor(s, 32); s += __shfl_xor(s, 16); s += __shfl_xor(s, 8);
  s += __shfl_xor(s, 4);  s += __shfl_xor(s, 2);  s += __shfl_xor(s, 1);
  if (lane == 0){
    float a = s + b_c[0];
    float cz = sigmoidf_(a);
    out[DF + r] = cz;
    out[DF + NN + r] = (cz > 0.7f) ? 1.f : 0.f;
  }
}

__global__ void k_gfeat(const unsigned short* __restrict__ h, float* __restrict__ out){
  int col = blockIdx.x*256 + threadIdx.x;
  int r0 = blockIdx.y * 512;
  float s = 0.f;
  for (int r = r0; r < r0 + 512; r++) s += bf2f(h[(size_t)r*DF + col]);
  atomicAdd(&out[col], s * (1.f/8192.f));
}

// ---------------- launch ----------------
extern "C" void kernel_launch(void* const* d_in, const int* in_sizes, int n_in,
                              void* d_out, int out_size, void* d_ws, size_t ws_size,
                              hipStream_t stream) {
  const float* node_feats = (const float*)d_in[0];
  const int*   timestamps = (const int*)d_in[1];
  const int*   ei         = (const int*)d_in[2];
  const int*   e_src = ei;
  const int*   e_dst = ei + NE_;
  const float* W_in    = (const float*)d_in[3];
  const float* conv_w  = (const float*)d_in[4];
  const float* conv_b  = (const float*)d_in[5];
  const float* W_xproj = (const float*)d_in[6];
  const float* W_dt    = (const float*)d_in[7];
  const float* b_dt    = (const float*)d_in[8];
  const float* A_log   = (const float*)d_in[9];
  const float* D_param = (const float*)d_in[10];
  const float* W_out   = (const float*)d_in[11];
  const float* Wg      = (const float*)d_in[12];
  const float* bg      = (const float*)d_in[13];
  const float* W_c     = (const float*)d_in[14];
  const float* b_c     = (const float*)d_in[15];
  float* out = (float*)d_out;

  char* ws = (char*)d_ws;
  size_t off = 0;
  auto alloc = [&](size_t bytes) -> char* {
    char* p = ws + off; off += (bytes + 255) & ~(size_t)255; return p;
  };
  unsigned short* WinT   = (unsigned short*)alloc((size_t)3072*768*2);
  unsigned short* WxT    = (unsigned short*)alloc((size_t)128*1536*2);
  unsigned short* WdtT   = (unsigned short*)alloc((size_t)1536*64*2);
  unsigned short* WoutT  = (unsigned short*)alloc((size_t)768*1536*2);
  unsigned short* WgT    = (unsigned short*)alloc((size_t)3*768*768*2);
  unsigned short* seq    = (unsigned short*)alloc((size_t)NN*DF*2);
  unsigned short* xz     = (unsigned short*)alloc((size_t)NN*3072*2);
  unsigned short* ubuf   = (unsigned short*)alloc((size_t)NN*DIM*2);
  float*          dbc    = (float*)alloc((size_t)NN*128*4);
  unsigned short* dt48   = (unsigned short*)alloc((size_t)NN*64*2);
  unsigned short* deltaB = (unsigned short*)alloc((size_t)NN*DIM*2);  // bf16 now
  unsigned short* ybuf   = (unsigned short*)alloc((size_t)NN*DIM*2);
  unsigned short* hbuf   = (unsigned short*)alloc((size_t)NN*DF*2);
  unsigned short* mbuf   = (unsigned short*)alloc((size_t)NN*DF*2);
  int*   pos    = (int*)alloc((size_t)NN*4);
  int*   degS   = (int*)alloc((size_t)2*NN*4);
  int*   degD   = degS + NN;
  float* normS  = (float*)alloc((size_t)NN*4);
  float* normD  = (float*)alloc((size_t)NN*4);
  int*   rowp   = (int*)alloc((size_t)(NN+1)*4);
  int*   cursor = (int*)alloc((size_t)NN*4);
  int*   csr    = (int*)alloc((size_t)NE_*4);

  // scan chunk summaries (12.58 MB each): hend aliases seq (dead after G1);
  // aprod aliases mbuf (first written by k_aggregate, after the scan)
  float* hend  = (float*)seq;
  float* aprod = (float*)mbuf;

  // zero-init accumulated buffers every call (harness poisons ws/d_out once)
  hipMemsetAsync(degS, 0, (size_t)2*NN*4, stream);
  hipMemsetAsync(pos, 0, (size_t)NN*4, stream);
  hipMemsetAsync(out, 0, (size_t)DF*4, stream);

  // all weight transposes in one launch
  k_prep<<<21888, 256, 0, stream>>>(W_in, W_xproj, W_dt, W_out, Wg,
                                    WinT, WxT, WdtT, WoutT, WgT);

  // sort + gather (rank 2D-parallel: 32x32 blocks)
  k_rank<<<dim3(NN/256, NN/256), 256, 0, stream>>>(timestamps, pos);
  k_gather<<<NN, 256, 0, stream>>>(node_feats, pos, seq);

  // graph structure
  k_deg_count<<<NE_/256, 256, 0, stream>>>(e_src, e_dst, degS, degD);
  k_norms<<<NN/256, 256, 0, stream>>>(degS, degD, normS, normD);
  k_rowptr<<<1, 1024, 0, stream>>>(degD, rowp, cursor);
  k_csr_fill<<<NE_/256, 256, 0, stream>>>(e_src, e_dst, cursor, csr);

  // G1: xz = seq @ W_in  (8192x3072, K=768)
  k_gemm<0><<<64*24, 256, 0, stream>>>(seq, WinT, 3072, 768, 768, 768,
                                       nullptr, 0, xz, 3072, nullptr, nullptr);
  // conv + silu -> u
  k_conv_silu<<<dim3(6, NN), 256, 0, stream>>>(xz, conv_w, conv_b, ubuf);
  // G2: dbc = u @ W_xproj  (8192x128pad, K=1536); also dt48 bf16 (cols<48)
  k_gemm<1><<<64*1, 256, 0, stream>>>(ubuf, WxT, 128, 1536, 1536, 1536,
                                      dbc, 128, nullptr, 0, nullptr, dt48);
  // G3: delta = softplus(dt48 @ W_dt + b_dt) -> bf16  (8192x1536, K=64)
  k_gemm<2><<<64*12, 256, 0, stream>>>(dt48, WdtT, 1536, 64, 64, 64,
                                       nullptr, 0, deltaB, 1536, b_dt, nullptr);
  // chunked scan -> y (fused (y + u*D)*silu(z))
  k_scanA<<<dim3(DIM/256, NCH), 256, 0, stream>>>(deltaB, ubuf, dbc, A_log, hend, aprod);
  k_scanB<<<96, 256, 0, stream>>>(hend, aprod);
  k_scanC<<<dim3(DIM/256, NCH), 256, 0, stream>>>(deltaB, ubuf, xz, dbc, A_log, D_param, hend, ybuf);
  // G4: h = y @ W_out  (8192x768, K=1536)
  k_gemm<0><<<64*6, 256, 0, stream>>>(ybuf, WoutT, 768, 1536, 1536, 1536,
                                      nullptr, 0, hbuf, 768, nullptr, nullptr);
  // 3 GCN layers
  for (int i = 0; i < 3; i++){
    k_aggregate<<<NN, 192, 0, stream>>>(hbuf, rowp, csr, normS, normD, mbuf);
    k_gemm<3><<<64*6, 256, 0, stream>>>(mbuf, WgT + (size_t)i*768*768, 768, 768, 768, 768,
                                        nullptr, 0, hbuf, 768, bg + (size_t)i*768, nullptr);
  }
  // finals
  k_causal<<<NN/4, 256, 0, stream>>>(hbuf, W_c, b_c, out);
  k_gfeat<<<dim3(3, 16), 256, 0, stream>>>(hbuf, out);
}